// Round 14
// baseline (192.673 us; speedup 1.0000x reference)
//
#include <hip/hip_runtime.h>
#include <hip/hip_fp16.h>

// KbInterpForw: table-based KB NUFFT interpolation, forward.
// x: (2,16,2,512,512) f32, om: (2,2,262144) f32, tables: (2,6145) f32 each.
// out: (2,16,2,262144) f32.
//
// R20 (on R19's 190.6 us):
//  - interp_bins async-STAGE split (T14): issue the 3-4 staging
//    global_load_dwordx4 into named registers FIRST, run the whole per-point
//    setup (som read, table loads, loff, sincos) while they fly, then
//    ds_write + barrier + pure tap loop. Setup (~100 inst/thread) now hides
//    the staging HBM/L2 latency instead of following it. Stage regs are
//    statically indexed (rule: dynamic-indexed reg arrays spill to scratch).
//    Overflow batches (cnt>256, rare) use the same setup/taps helpers
//    inline. Tap stream unchanged -> bit-identical output.
//  - Sort pipeline (R19 block-major blockHist), tile layout, unsort frozen.

#define KLEN      262144      // 2^18
#define GX        512
#define GY        512
#define NCOILS    16
#define NBATCH    2
#define TBL_LEN   6145        // 6*1024+1
#define TBL_CTR   3072
#define PLANE     (GX*GY)
#define NPTS      (NBATCH*KLEN)
#define NBINS     2048        // NBATCH * 32*32 tiles
#define NBLK      256         // sort blocks
#define PPB       2048        // points per sort block (NPTS/NBLK)
#define TBLKS     (NBATCH*PLANE/256)   // 2048 transpose blocks

#define TROWS     21          // 16 + 5 halo
#define TQ        5           // float4 slots per record in LDS (4 used + 1 pad)
#define TTOT      (TROWS*TROWS*4)      // 1764 staged float4 chunks

typedef _Float16 half2_t __attribute__((ext_vector_type(2)));
struct alignas(16) H8 { half2_t h[4]; };   // 4 coils' (re,im) fp16 = 16 B

// ---------------------------------------------------------------------------
// ws layout (bytes). blockHist aliases osort (dead before interp writes
// osort). btot/bbase live in the unaliased gap after osort.
// ---------------------------------------------------------------------------
#define WS_XT       0                         // 33554432  fp16 grid records
#define WS_OSORT    33554432                  // 33554432  fp16 sorted outputs
#define WS_BHIST    33554432                  //  2097152  u32 [NBLK][NBINS] (alias osort)
#define WS_BTOT     67108864                  //     8192  u32 [NBINS]  NOT aliased
#define WS_BBASE    (67108864+8192)           //     8192  u32 [NBINS]  NOT aliased
#define WS_INV      69206016                  //  2097152  u32 pos per point id
#define WS_SOM      71303168                  //  4194304  float2 om per pos
#define WS_TOTAL    75497472

__device__ inline int point_bin(float om0, float om1)
{
    const float TWO_PI = 6.2831853071795864769f;
    const float tm0 = (om0 * 512.0f) / TWO_PI;
    const float tm1 = (om1 * 512.0f) / TWO_PI;
    const int cx = ((int)floorf(tm0)) & 511;
    const int cy = ((int)floorf(tm1)) & 511;
    return ((cx >> 4) << 5) | (cy >> 4);      // [0, 1024)
}

// quad-perm broadcast of a 32-bit value with explicit control byte. VALU op.
// Sources must be active lanes (we only reference the reader's own pair).
template<int CTRL>
__device__ inline int qbci(int i)
{
    return __builtin_amdgcn_mov_dpp(i, CTRL, 0xf, 0xf, true);
}
#define DPP_EVEN 0xA0   // [0,0,2,2]: read even lane of own pair
#define DPP_ODD  0xF5   // [1,1,3,3]: read odd lane of own pair

__device__ inline half2_t h2bits(int i)
{
    half2_t r;
    __builtin_memcpy(&r, &i, 4);
    return r;
}

// ---------------------------------------------------------------------------
// Fused transpose+hist. Blocks [0, TBLKS): transpose 256 consecutive cells
// via LDS. Blocks [TBLKS, TBLKS+NBLK): per-block LDS histogram ->
// blockHist[blk][NBINS] (block-major, coalesced writeout). Pass
// blockHist=nullptr (grid=TBLKS) to run transpose only (middle path).
// ---------------------------------------------------------------------------
__global__ __launch_bounds__(256) void transpose_hist(
    const float* __restrict__ x, float4* __restrict__ xt,
    const float* __restrict__ om, unsigned* __restrict__ blockHist)
{
    __shared__ float s[32][260];   // 33280 B; hist aliases first 8192 B
    const int t = threadIdx.x;

    if (blockHist != nullptr && blockIdx.x >= TBLKS) {
        // ---- histogram body (256 threads, 8 iters) ----------------------
        unsigned* h = (unsigned*)s;               // [NBINS]
        const int blk = blockIdx.x - TBLKS;
#pragma unroll
        for (int i = 0; i < NBINS / 256; ++i) h[t + i * 256] = 0u;
        __syncthreads();
#pragma unroll
        for (int i = 0; i < PPB / 256; ++i) {
            const int id = blk * PPB + i * 256 + t;
            const int b = id >> 18, m = id & (KLEN - 1);
            const float om0 = om[(size_t)(b * 2 + 0) * KLEN + m];
            const float om1 = om[(size_t)(b * 2 + 1) * KLEN + m];
            const int g = (b << 10) | point_bin(om0, om1);
            atomicAdd(&h[g], 1u);
        }
        __syncthreads();
#pragma unroll
        for (int i = 0; i < NBINS / 256; ++i) {
            const int bin = t + i * 256;
            blockHist[(size_t)blk * NBINS + bin] = h[bin];   // coalesced row
        }
        return;
    }

    // ---- transpose body -------------------------------------------------
    const int blk   = blockIdx.x;            // [0, TBLKS)
    const int base  = blk * 256;
    const int b     = base >> 18;
    const int cell0 = base & (PLANE - 1);

    const float* xb = x + (size_t)b * 32 * PLANE + cell0;
#pragma unroll
    for (int i = 0; i < 8; ++i) {
        const int fidx = i * 256 + t;        // [0, 2048)
        const int pl = fidx >> 6;            // wave-uniform plane
        const int j  = fidx & 63;
        const float4 v = *(const float4*)(xb + (size_t)pl * PLANE + j * 4);
        *(float4*)&s[pl][j * 4] = v;
    }
    __syncthreads();
#pragma unroll
    for (int i = 0; i < 4; ++i) {
        const int chunk = i * 256 + t;       // [0, 1024)
        const int cell = chunk >> 2, q = chunk & 3;
        H8 rec;
#pragma unroll
        for (int cc = 0; cc < 4; ++cc) {
            const int c = q * 4 + cc;
            rec.h[cc] = half2_t{(_Float16)s[2 * c][cell],
                                (_Float16)s[2 * c + 1][cell]};
        }
        xt[((size_t)b * PLANE + cell0 + cell) * 4 + q] = *(const float4*)&rec;
    }
}

// ---------------------------------------------------------------------------
// Sort pass 2: exclusive scan over blocks for each bin, block-major layout.
// Each block handles 16 consecutive bins: LDS-transpose a 256x16 panel
// (coalesced loads/stores), wave w scans bin column w via __shfl_up.
// Grid = NBINS/16 = 128 blocks x 1024 threads.
// ---------------------------------------------------------------------------
__global__ __launch_bounds__(1024) void scan_bins(
    unsigned* __restrict__ blockHist, unsigned* __restrict__ binTotal)
{
    __shared__ unsigned sh[256][17];          // [sortblk][bin-in-group]+pad
    const int t    = threadIdx.x;
    const int bin0 = blockIdx.x * 16;
    const int col  = t & 15, row0 = t >> 4;   // 64 rows per pass
#pragma unroll
    for (int p = 0; p < 4; ++p) {
        const int row = row0 + p * 64;
        sh[row][col] = blockHist[(size_t)row * NBINS + bin0 + col];
    }
    __syncthreads();

    const int lane = t & 63, wave = t >> 6;   // wave w owns bin0+w
    unsigned v[4];
#pragma unroll
    for (int k = 0; k < 4; ++k) v[k] = sh[lane * 4 + k][wave];
    const unsigned tot = v[0] + v[1] + v[2] + v[3];
    unsigned s = tot;
#pragma unroll
    for (int d = 1; d < 64; d <<= 1) {
        const unsigned x = __shfl_up(s, d);
        if (lane >= d) s += x;
    }
    unsigned excl = s - tot;                  // prefix for lane's 4 rows
#pragma unroll
    for (int k = 0; k < 4; ++k) { const unsigned nv = excl; excl += v[k]; v[k] = nv; }
    __syncthreads();                          // reuse sh for writeback
#pragma unroll
    for (int k = 0; k < 4; ++k) sh[lane * 4 + k][wave] = v[k];
    if (lane == 63) binTotal[bin0 + wave] = s;
    __syncthreads();
#pragma unroll
    for (int p = 0; p < 4; ++p) {
        const int row = row0 + p * 64;
        blockHist[(size_t)row * NBINS + bin0 + col] = sh[row][col];
    }
}

// ---------------------------------------------------------------------------
// Sort pass 3: final positions. Wave-based scan of btot gives bin bases;
// the block's own blockHist row (exclusive prefix over blocks) is folded
// into bbs at preamble time, so the per-point lookup is LDS-only.
// Block 0 publishes pure bin bases to global bbase for interp. 1024 thr.
// ---------------------------------------------------------------------------
__global__ __launch_bounds__(1024) void scatter2(
    const float*    __restrict__ om,
    const unsigned* __restrict__ blockHist,
    const unsigned* __restrict__ btot,
    unsigned* __restrict__ bbase,
    unsigned* __restrict__ inv,
    float2* __restrict__ som)
{
    __shared__ unsigned h[NBINS];
    __shared__ unsigned bbs[NBINS];
    __shared__ unsigned wsum[16];
    const int t = threadIdx.x, blk = blockIdx.x;
    const int lane = t & 63, wave = t >> 6;

    // exclusive scan of btot -> bin bases: wave scan + 1-barrier fixup
    const unsigned v0 = btot[t * 2], v1 = btot[t * 2 + 1];
    const unsigned tot = v0 + v1;
    unsigned s = tot;
#pragma unroll
    for (int d = 1; d < 64; d <<= 1) {
        const unsigned x = __shfl_up(s, d);
        if (lane >= d) s += x;
    }
    if (lane == 63) wsum[wave] = s;
    // own row of scanned blockHist (coalesced 8 KB)
    const unsigned bh0 = blockHist[(size_t)blk * NBINS + t * 2];
    const unsigned bh1 = blockHist[(size_t)blk * NBINS + t * 2 + 1];
#pragma unroll
    for (int i = 0; i < NBINS / 1024; ++i) h[t + i * 1024] = 0u;
    __syncthreads();
    unsigned wp = 0;
#pragma unroll
    for (int i = 0; i < 16; ++i) wp += (i < wave) ? wsum[i] : 0u;
    const unsigned excl = wp + s - tot;
    bbs[t * 2]     = excl + bh0;              // binbase + row prefix folded
    bbs[t * 2 + 1] = excl + v0 + bh1;
    if (blk == 0) {                           // publish pure bases for interp
        bbase[t * 2]     = excl;
        bbase[t * 2 + 1] = excl + v0;
    }
    __syncthreads();

#pragma unroll
    for (int i = 0; i < PPB / 1024; ++i) {
        const int id = blk * PPB + i * 1024 + t;
        const int b = id >> 18, m = id & (KLEN - 1);
        const float om0 = om[(size_t)(b * 2 + 0) * KLEN + m];
        const float om1 = om[(size_t)(b * 2 + 1) * KLEN + m];
        const int g = (b << 10) | point_bin(om0, om1);
        const unsigned r = atomicAdd(&h[g], 1u);
        const unsigned pos = bbs[g] + r;       // LDS-only lookup
        inv[id]  = pos;                        // coalesced
        som[pos] = make_float2(om0, om1);      // scattered 8 B
    }
}

// ---------------------------------------------------------------------------
// interp helpers: per-point setup (tile-independent) and tap loop.
// ---------------------------------------------------------------------------
struct PSet {
    float c0r[6];
    float c1w[3];
    int   loff[6];
    int   k0;
    float sn, cs;
};

__device__ __forceinline__ PSet kb_setup(
    const float2 o, const int cy0, const int lane,
    const float* __restrict__ t0, const float* __restrict__ t1)
{
    PSet ps;
    const float om0 = o.x, om1 = o.y;
    const float TWO_PI = 6.2831853071795864769f;
    const float tm0 = (om0 * 512.0f) / TWO_PI;
    const float tm1 = (om1 * 512.0f) / TWO_PI;
    const float koff0 = 1.0f + floorf(tm0 - 3.0f);
    const float koff1 = 1.0f + floorf(tm1 - 3.0f);
    ps.k0 = (int)koff0;
    const int k1 = (int)koff1;
#pragma unroll
    for (int j = 0; j < 6; ++j) {
        const float g0 = koff0 + (float)j;
        const int   d0 = (int)rintf((tm0 - g0) * 1024.0f) + TBL_CTR;
        ps.c0r[j] = t0[d0];
        ps.loff[j] = ((k1 + j - cy0 + 2) & 511) * TQ;    // in [0, 20]*TQ
    }
    const int j1o = 3 * lane;                 // own j1 base: 0 or 3
#pragma unroll
    for (int k = 0; k < 3; ++k) {
        const int d1 = (int)rintf((tm1 - (koff1 + (float)(j1o + k))) * 1024.0f)
                       + TBL_CTR;
        ps.c1w[k] = t1[d1];
    }
    const float ph = om0 * 128.0f + om1 * 128.0f;
    ps.sn = __sinf(ph);
    ps.cs = __cosf(ph);
    return ps;
}

__device__ __forceinline__ void kb_taps(
    const PSet& ps, const float4* __restrict__ tile,
    const int lane, const int cx0, float4* __restrict__ op)
{
    // acr[0..3]: slot (lane)   -> coils 4*lane   .. 4*lane+3
    // acr[4..7]: slot (lane+2) -> coils 4*lane+8 .. 4*lane+11
    float acr[8], aci[8];
#pragma unroll
    for (int c = 0; c < 8; ++c) { acr[c] = 0.f; aci[c] = 0.f; }

#define KB_DO_J1(JJ, P1, P2)                                                  \
    do {                                                                      \
        const half2_t p1 = (P1);                                              \
        const half2_t p2 = (P2);                                              \
        const float4 raw0 = rowp[ps.loff[JJ]];                                \
        const float4 raw1 = rowp[ps.loff[JJ] + 2];                            \
        const H8 v0 = *(const H8*)&raw0;                                      \
        const H8 v1 = *(const H8*)&raw1;                                      \
        _Pragma("unroll")                                                     \
        for (int cc = 0; cc < 4; ++cc) {                                      \
            acr[cc]   = __builtin_amdgcn_fdot2(v0.h[cc], p1, acr[cc],   false);\
            aci[cc]   = __builtin_amdgcn_fdot2(v0.h[cc], p2, aci[cc],   false);\
            acr[4+cc] = __builtin_amdgcn_fdot2(v1.h[cc], p1, acr[4+cc], false);\
            aci[4+cc] = __builtin_amdgcn_fdot2(v1.h[cc], p2, aci[4+cc], false);\
        }                                                                     \
    } while (0)

#pragma unroll
    for (int j0 = 0; j0 < 6; ++j0) {
        const int rIdx = (ps.k0 + j0 - cx0 + 2) & 511;   // in [0, 20]
        const float4* rowp = &tile[rIdx * (TROWS * TQ) + lane];
        const float ar = ps.c0r[j0];
        // this lane's 3 real weights, packed fp16x2 (RNE casts)
        const float wA = ar * ps.c1w[0];
        const float wB = ar * ps.c1w[1];
        const float wC = ar * ps.c1w[2];
        const half2_t pk01 = {(_Float16)wA, (_Float16)wB};
        const half2_t pk2  = {(_Float16)wC, (_Float16)0.0f};
        int i01, i2;
        __builtin_memcpy(&i01, &pk01, 4);
        __builtin_memcpy(&i2,  &pk2, 4);
        // pair-share: 4 DPP broadcasts cover all 6 j1 weights
        const int e01 = qbci<DPP_EVEN>(i01);
        const int e2  = qbci<DPP_EVEN>(i2);
        const int o01 = qbci<DPP_ODD >(i01);
        const int o2  = qbci<DPP_ODD >(i2);

        // j1 slot weights: (w,0) for re-acc, (0,w) for im-acc
        KB_DO_J1(0, h2bits(e01 & 0xffff),       h2bits(e01 << 16));
        KB_DO_J1(1, h2bits((int)((unsigned)e01 >> 16)), h2bits(e01 & (int)0xffff0000u));
        KB_DO_J1(2, h2bits(e2 & 0xffff),        h2bits(e2 << 16));
        KB_DO_J1(3, h2bits(o01 & 0xffff),       h2bits(o01 << 16));
        KB_DO_J1(4, h2bits((int)((unsigned)o01 >> 16)), h2bits(o01 & (int)0xffff0000u));
        KB_DO_J1(5, h2bits(o2 & 0xffff),        h2bits(o2 << 16));
    }
#undef KB_DO_J1

    // phase twist + output (even lane slots 0,2; odd 1,3)
#pragma unroll
    for (int q = 0; q < 2; ++q) {
        H8 outrec;
#pragma unroll
        for (int cc = 0; cc < 4; ++cc) {
            const int a = q * 4 + cc;
            const float yr = acr[a] * ps.cs - aci[a] * ps.sn;
            const float yi = acr[a] * ps.sn + aci[a] * ps.cs;
            outrec.h[cc] = half2_t{(_Float16)yr, (_Float16)yi};
        }
        op[q * 2] = *(const float4*)&outrec;
    }
}

// ---------------------------------------------------------------------------
// Main interp: ONE BLOCK PER BIN, 512 threads. ASYNC-STAGE SPLIT: issue the
// 3-4 staging loads into registers, run first-batch point setup while they
// fly, then ds_write + barrier + tap loop. Tile: proven TQ=5 record-pad
// layout. 2 lanes/point x 8 coils, real-table weights, DPP pair-share.
// ---------------------------------------------------------------------------
__global__ __launch_bounds__(512) void interp_bins(
    const float2*   __restrict__ som,
    const float*    __restrict__ t0,
    const float*    __restrict__ t1,
    const float4*   __restrict__ xt,
    const unsigned* __restrict__ bbase,
    float4*         __restrict__ osort)
{
    __shared__ float4 tile[TROWS * TROWS * TQ];   // 2205 f4 = 35280 B
    const int bin = blockIdx.x;
    const int t   = threadIdx.x;
    const int b   = bin >> 10;
    const int cx0 = ((bin >> 5) & 31) << 4;
    const int cy0 = (bin & 31) << 4;

    const unsigned p0  = bbase[bin];
    const unsigned p1e = (bin == NBINS - 1) ? (unsigned)NPTS : bbase[bin + 1];
    const int cnt = (int)(p1e - p0);
    const int lane = t & 1;                    // pair lane

    // ---- phase A: issue stage loads into named registers ----------------
    const float4* rec = xt + ((size_t)b << 20);   // b * PLANE * 4 chunks
#define STAGE_ADDR(F, SV, SO)                                                 \
    do {                                                                      \
        const int r_ = (F) >> 2, q_ = (F) & 3;                                \
        const int row_ = r_ / TROWS;                                          \
        const int col_ = r_ - row_ * TROWS;                                   \
        const int gr_ = (cx0 - 2 + row_) & 511;                               \
        const int gc_ = (cy0 - 2 + col_) & 511;                               \
        SV = rec[(((size_t)((gr_ << 9) | gc_)) << 2) + q_];                   \
        SO = r_ * TQ + q_;                                                    \
    } while (0)
    float4 sv0, sv1, sv2, sv3;
    int so0, so1, so2, so3 = -1;
    STAGE_ADDR(t,        sv0, so0);
    STAGE_ADDR(t + 512,  sv1, so1);
    STAGE_ADDR(t + 1024, sv2, so2);
    if (t + 1536 < TTOT) STAGE_ADDR(t + 1536, sv3, so3);
#undef STAGE_ADDR

    // ---- phase B: first-batch setup (tile-independent, hides load lat) --
    const int idx0 = t >> 1;
    const bool v0 = (idx0 < cnt);
    const int pos0 = (int)p0 + idx0;
    PSet ps;
    if (v0) ps = kb_setup(som[pos0], cy0, lane, t0, t1);

    // ---- phase C: LDS writes + barrier ----------------------------------
    tile[so0] = sv0;
    tile[so1] = sv1;
    tile[so2] = sv2;
    if (so3 >= 0) tile[so3] = sv3;
    __syncthreads();

    // ---- phase D: first batch (precomputed setup) -----------------------
    if (v0) kb_taps(ps, tile, lane, cx0, osort + (size_t)pos0 * 4 + lane);

    // ---- overflow batches (cnt > 256, rare Poisson tail) ----------------
    for (int base = 256; base < cnt; base += 256) {
        const int idx = base + (t >> 1);
        if (idx >= cnt) continue;              // lane-pairs skip together
        const int pos = (int)p0 + idx;
        const PSet ps2 = kb_setup(som[pos], cy0, lane, t0, t1);
        kb_taps(ps2, tile, lane, cx0, osort + (size_t)pos * 4 + lane);
    }
}

// ---------------------------------------------------------------------------
// Unsort: thread per point id; gather 64 B record from osort, store coalesced
// into final (b,c,ri,m) layout. 1024 threads for gather-latency hiding.
// ---------------------------------------------------------------------------
__global__ __launch_bounds__(1024) void unsort_kernel(
    const unsigned* __restrict__ inv,
    const float4*   __restrict__ osort,
    float*          __restrict__ out)
{
    const int id = blockIdx.x * blockDim.x + threadIdx.x;   // [0, NPTS)
    const int b = id >> 18, m = id & (KLEN - 1);
    const unsigned pos = inv[id];
    const float4* rp = osort + (size_t)pos * 4;

    float4 raw[4];
#pragma unroll
    for (int q = 0; q < 4; ++q) raw[q] = rp[q];

    float* ob = out + (size_t)b * NCOILS * 2 * KLEN + m;
#pragma unroll
    for (int q = 0; q < 4; ++q) {
        const H8 v = *(const H8*)&raw[q];
#pragma unroll
        for (int cc = 0; cc < 4; ++cc) {
            const int coil = q * 4 + cc;
            ob[(size_t)(2 * coil)     * KLEN] = (float)v.h[cc].x;
            ob[(size_t)(2 * coil + 1) * KLEN] = (float)v.h[cc].y;
        }
    }
}

// ---------------------------------------------------------------------------
// Middle path (ws >= xt only): direct-order interp (4 lanes/point).
// Keeps the general complex-table math (not perf-critical).
// ---------------------------------------------------------------------------
__global__ __launch_bounds__(256) void interp_direct(
    const float*  __restrict__ om,
    const float*  __restrict__ t0,
    const float*  __restrict__ t1,
    const float4* __restrict__ xt,
    float*        __restrict__ out)
{
    const int tid  = blockIdx.x * blockDim.x + threadIdx.x;
    const int lane = tid & 3;
    const int p    = tid >> 2;
    const int b    = p >> 18;
    const int m    = p & (KLEN - 1);

    const float om0 = om[(size_t)(b * 2 + 0) * KLEN + m];
    const float om1 = om[(size_t)(b * 2 + 1) * KLEN + m];

    const float TWO_PI = 6.2831853071795864769f;
    const float tm0 = (om0 * 512.0f) / TWO_PI;
    const float tm1 = (om1 * 512.0f) / TWO_PI;
    const float koff0 = 1.0f + floorf(tm0 - 3.0f);
    const float koff1 = 1.0f + floorf(tm1 - 3.0f);
    const int k0 = (int)koff0, k1 = (int)koff1;

    float c0r[6], c0i[6], c1r[6], c1i[6];
    int coff[6];
#pragma unroll
    for (int j = 0; j < 6; ++j) {
        const float g0 = koff0 + (float)j;
        const int d0 = (int)rintf((tm0 - g0) * 1024.0f) + TBL_CTR;
        c0r[j] = t0[d0];
        c0i[j] = t0[TBL_LEN + d0];
        const float g1 = koff1 + (float)j;
        const int d1 = (int)rintf((tm1 - g1) * 1024.0f) + TBL_CTR;
        c1r[j] = t1[d1];
        c1i[j] = t1[TBL_LEN + d1];
        coff[j] = ((k1 + j) & 511) << 2;
    }

    const float4* rec = xt + ((size_t)b << 20);
    float acr[4] = {0.f, 0.f, 0.f, 0.f};
    float aci[4] = {0.f, 0.f, 0.f, 0.f};
#pragma unroll
    for (int j0 = 0; j0 < 6; ++j0) {
        const int roff = (k0 + j0) & 511;
        const float4* rowp = rec + ((size_t)roff << 11) + lane;
        const float ar = c0r[j0], ai = c0i[j0];
#pragma unroll
        for (int j1 = 0; j1 < 6; ++j1) {
            const float br = c1r[j1], bi = c1i[j1];
            const float cr = ar * br - ai * bi;
            const float ci = ar * bi + ai * br;
            const half2_t p1 = {(_Float16)cr, (_Float16)(-ci)};
            const half2_t p2 = {(_Float16)ci, (_Float16)cr};
            const float4 raw = rowp[coff[j1]];
            const H8 v = *(const H8*)&raw;
#pragma unroll
            for (int cc = 0; cc < 4; ++cc) {
                acr[cc] = __builtin_amdgcn_fdot2(v.h[cc], p1, acr[cc], false);
                aci[cc] = __builtin_amdgcn_fdot2(v.h[cc], p2, aci[cc], false);
            }
        }
    }

    const float ph = om0 * 128.0f + om1 * 128.0f;
    const float s = sinf(ph), c = cosf(ph);
#pragma unroll
    for (int cc = 0; cc < 4; ++cc) {
        const float yr = acr[cc] * c - aci[cc] * s;
        const float yi = acr[cc] * s + aci[cc] * c;
        const int coil = lane * 4 + cc;
        const size_t ob = ((size_t)(b * NCOILS + coil) * 2) * KLEN + m;
        out[ob]        = yr;
        out[ob + KLEN] = yi;
    }
}

// ---------------------------------------------------------------------------
// Fallback (tiny ws): one thread per point, original layout. General math.
// ---------------------------------------------------------------------------
__global__ __launch_bounds__(256) void interp_fallback(
    const float* __restrict__ om,
    const float* __restrict__ t0,
    const float* __restrict__ t1,
    const float* __restrict__ x,
    float*       __restrict__ out)
{
    const int p = blockIdx.x * blockDim.x + threadIdx.x;
    const int b = p >> 18;
    const int m = p & (KLEN - 1);

    const float om0 = om[(size_t)(b * 2 + 0) * KLEN + m];
    const float om1 = om[(size_t)(b * 2 + 1) * KLEN + m];
    const float TWO_PI = 6.2831853071795864769f;
    const float tm0 = (om0 * 512.0f) / TWO_PI;
    const float tm1 = (om1 * 512.0f) / TWO_PI;
    const float koff0 = 1.0f + floorf(tm0 - 3.0f);
    const float koff1 = 1.0f + floorf(tm1 - 3.0f);
    const int k0 = (int)koff0, k1 = (int)koff1;

    float c0r[6], c0i[6], c1r[6], c1i[6];
    int roff[6], coff[6];
#pragma unroll
    for (int j = 0; j < 6; ++j) {
        const float g0 = koff0 + (float)j;
        const int d0 = (int)rintf((tm0 - g0) * 1024.0f) + TBL_CTR;
        c0r[j] = t0[d0];
        c0i[j] = t0[TBL_LEN + d0];
        const float g1 = koff1 + (float)j;
        const int d1 = (int)rintf((tm1 - g1) * 1024.0f) + TBL_CTR;
        c1r[j] = t1[d1];
        c1i[j] = t1[TBL_LEN + d1];
        roff[j] = (k0 + j) & 511;
        coff[j] = (k1 + j) & 511;
    }

    float accr[NCOILS], acci[NCOILS];
#pragma unroll
    for (int c = 0; c < NCOILS; ++c) { accr[c] = 0.f; acci[c] = 0.f; }

    const float* xb = x + (size_t)b * NCOILS * 2 * PLANE;
#pragma unroll
    for (int j0 = 0; j0 < 6; ++j0) {
        const float ar = c0r[j0], ai = c0i[j0];
        const int rb = roff[j0] * GY;
#pragma unroll
        for (int j1 = 0; j1 < 6; ++j1) {
            const float br = c1r[j1], bi = c1i[j1];
            const float cr = ar * br - ai * bi;
            const float ci = ar * bi + ai * br;
            const int ai_idx = rb + coff[j1];
#pragma unroll
            for (int c = 0; c < NCOILS; ++c) {
                const float dr = xb[(size_t)c * (2 * PLANE) + ai_idx];
                const float di = xb[(size_t)c * (2 * PLANE) + PLANE + ai_idx];
                accr[c] += cr * dr - ci * di;
                acci[c] += cr * di + ci * dr;
            }
        }
    }

    const float ph = om0 * 128.0f + om1 * 128.0f;
    const float s = sinf(ph), c = cosf(ph);
#pragma unroll
    for (int cc = 0; cc < NCOILS; ++cc) {
        const float yr = accr[cc] * c - acci[cc] * s;
        const float yi = accr[cc] * s + acci[cc] * c;
        size_t ob = ((size_t)(b * NCOILS + cc) * 2) * KLEN + m;
        out[ob]        = yr;
        out[ob + KLEN] = yi;
    }
}

extern "C" void kernel_launch(void* const* d_in, const int* in_sizes, int n_in,
                              void* d_out, int out_size, void* d_ws, size_t ws_size,
                              hipStream_t stream)
{
    const float* x  = (const float*)d_in[0];
    const float* om = (const float*)d_in[1];
    const float* t0 = (const float*)d_in[2];
    const float* t1 = (const float*)d_in[3];
    float* out = (float*)d_out;

    char* ws = (char*)d_ws;
    const size_t xt_bytes = (size_t)NBATCH * PLANE * NCOILS * 2 * sizeof(__half);

    if (ws_size >= (size_t)WS_TOTAL) {
        float4*   xt     = (float4*)(ws + WS_XT);
        float4*   osort  = (float4*)(ws + WS_OSORT);
        unsigned* bhist  = (unsigned*)(ws + WS_BHIST);
        unsigned* btot   = (unsigned*)(ws + WS_BTOT);
        unsigned* bbase  = (unsigned*)(ws + WS_BBASE);
        unsigned* inv    = (unsigned*)(ws + WS_INV);
        float2*   som    = (float2*)(ws + WS_SOM);

        transpose_hist<<<TBLKS + NBLK, 256, 0, stream>>>(x, xt, om, bhist);
        scan_bins<<<NBINS / 16, 1024, 0, stream>>>(bhist, btot);
        scatter2<<<NBLK, 1024, 0, stream>>>(om, bhist, btot, bbase, inv, som);
        interp_bins<<<NBINS, 512, 0, stream>>>(som, t0, t1, xt, bbase, osort);
        unsort_kernel<<<NPTS / 1024, 1024, 0, stream>>>(inv, osort, out);
    } else if (ws_size >= xt_bytes) {
        float4* xt = (float4*)ws;
        transpose_hist<<<TBLKS, 256, 0, stream>>>(x, xt, om, nullptr);
        interp_direct<<<NPTS * 4 / 256, 256, 0, stream>>>(om, t0, t1, xt, out);
    } else {
        interp_fallback<<<NPTS / 256, 256, 0, stream>>>(om, t0, t1, x, out);
    }
}

// Round 15
// 191.285 us; speedup vs baseline: 1.0073x; 1.0073x over previous
//
#include <hip/hip_runtime.h>
#include <hip/hip_fp16.h>

// KbInterpForw: table-based KB NUFFT interpolation, forward.
// x: (2,16,2,512,512) f32, om: (2,2,262144) f32, tables: (2,6145) f32 each.
// out: (2,16,2,262144) f32.
//
// R21 (on R19's 190.6 us; R20's async-stage split was neutral -> reverted):
//  - interp_bins XCD-aware bin swizzle (T1): bin = (blk&7)<<8 | blk>>3.
//    Consecutive bins share ~72% of their 21x21 halo; default round-robin
//    dispatch put neighbors on different XCDs (private L2s), forcing halo
//    re-fetch through L3. Swizzled, each XCD owns 256 contiguous bins
//    (8 full tile rows) -> halo reuse hits local L2. 2048 % 8 == 0 ->
//    bijective. Output order unchanged (bin is just relabeled per block).
//  - Everything else frozen: R19 sort pipeline (block-major blockHist,
//    wave scans, LDS-only scatter), TQ=5 tile, 2-lane/8-coil real-weight
//    DPP interp, 1024-thread unsort.

#define KLEN      262144      // 2^18
#define GX        512
#define GY        512
#define NCOILS    16
#define NBATCH    2
#define TBL_LEN   6145        // 6*1024+1
#define TBL_CTR   3072
#define PLANE     (GX*GY)
#define NPTS      (NBATCH*KLEN)
#define NBINS     2048        // NBATCH * 32*32 tiles
#define NBLK      256         // sort blocks
#define PPB       2048        // points per sort block (NPTS/NBLK)
#define TBLKS     (NBATCH*PLANE/256)   // 8192 transpose blocks

#define TROWS     21          // 16 + 5 halo
#define TQ        5           // float4 slots per record in LDS (4 used + 1 pad)

typedef _Float16 half2_t __attribute__((ext_vector_type(2)));
struct alignas(16) H8 { half2_t h[4]; };   // 4 coils' (re,im) fp16 = 16 B

// ---------------------------------------------------------------------------
// ws layout (bytes). blockHist aliases osort (dead before interp writes
// osort). btot/bbase live in the unaliased gap after osort.
// ---------------------------------------------------------------------------
#define WS_XT       0                         // 33554432  fp16 grid records
#define WS_OSORT    33554432                  // 33554432  fp16 sorted outputs
#define WS_BHIST    33554432                  //  2097152  u32 [NBLK][NBINS] (alias osort)
#define WS_BTOT     67108864                  //     8192  u32 [NBINS]  NOT aliased
#define WS_BBASE    (67108864+8192)           //     8192  u32 [NBINS]  NOT aliased
#define WS_INV      69206016                  //  2097152  u32 pos per point id
#define WS_SOM      71303168                  //  4194304  float2 om per pos
#define WS_TOTAL    75497472

__device__ inline int point_bin(float om0, float om1)
{
    const float TWO_PI = 6.2831853071795864769f;
    const float tm0 = (om0 * 512.0f) / TWO_PI;
    const float tm1 = (om1 * 512.0f) / TWO_PI;
    const int cx = ((int)floorf(tm0)) & 511;
    const int cy = ((int)floorf(tm1)) & 511;
    return ((cx >> 4) << 5) | (cy >> 4);      // [0, 1024)
}

// quad-perm broadcast of a 32-bit value with explicit control byte. VALU op.
// Sources must be active lanes (we only reference the reader's own pair).
template<int CTRL>
__device__ inline int qbci(int i)
{
    return __builtin_amdgcn_mov_dpp(i, CTRL, 0xf, 0xf, true);
}
#define DPP_EVEN 0xA0   // [0,0,2,2]: read even lane of own pair
#define DPP_ODD  0xF5   // [1,1,3,3]: read odd lane of own pair

__device__ inline half2_t h2bits(int i)
{
    half2_t r;
    __builtin_memcpy(&r, &i, 4);
    return r;
}

// ---------------------------------------------------------------------------
// Fused transpose+hist. Blocks [0, TBLKS): transpose 256 consecutive cells
// via LDS. Blocks [TBLKS, TBLKS+NBLK): per-block LDS histogram ->
// blockHist[blk][NBINS] (block-major, coalesced writeout). Pass
// blockHist=nullptr (grid=TBLKS) to run transpose only (middle path).
// ---------------------------------------------------------------------------
__global__ __launch_bounds__(256) void transpose_hist(
    const float* __restrict__ x, float4* __restrict__ xt,
    const float* __restrict__ om, unsigned* __restrict__ blockHist)
{
    __shared__ float s[32][260];   // 33280 B; hist aliases first 8192 B
    const int t = threadIdx.x;

    if (blockHist != nullptr && blockIdx.x >= TBLKS) {
        // ---- histogram body (256 threads, 8 iters) ----------------------
        unsigned* h = (unsigned*)s;               // [NBINS]
        const int blk = blockIdx.x - TBLKS;
#pragma unroll
        for (int i = 0; i < NBINS / 256; ++i) h[t + i * 256] = 0u;
        __syncthreads();
#pragma unroll
        for (int i = 0; i < PPB / 256; ++i) {
            const int id = blk * PPB + i * 256 + t;
            const int b = id >> 18, m = id & (KLEN - 1);
            const float om0 = om[(size_t)(b * 2 + 0) * KLEN + m];
            const float om1 = om[(size_t)(b * 2 + 1) * KLEN + m];
            const int g = (b << 10) | point_bin(om0, om1);
            atomicAdd(&h[g], 1u);
        }
        __syncthreads();
#pragma unroll
        for (int i = 0; i < NBINS / 256; ++i) {
            const int bin = t + i * 256;
            blockHist[(size_t)blk * NBINS + bin] = h[bin];   // coalesced row
        }
        return;
    }

    // ---- transpose body -------------------------------------------------
    const int blk   = blockIdx.x;            // [0, TBLKS)
    const int base  = blk * 256;
    const int b     = base >> 18;
    const int cell0 = base & (PLANE - 1);

    const float* xb = x + (size_t)b * 32 * PLANE + cell0;
#pragma unroll
    for (int i = 0; i < 8; ++i) {
        const int fidx = i * 256 + t;        // [0, 2048)
        const int pl = fidx >> 6;            // wave-uniform plane
        const int j  = fidx & 63;
        const float4 v = *(const float4*)(xb + (size_t)pl * PLANE + j * 4);
        *(float4*)&s[pl][j * 4] = v;
    }
    __syncthreads();
#pragma unroll
    for (int i = 0; i < 4; ++i) {
        const int chunk = i * 256 + t;       // [0, 1024)
        const int cell = chunk >> 2, q = chunk & 3;
        H8 rec;
#pragma unroll
        for (int cc = 0; cc < 4; ++cc) {
            const int c = q * 4 + cc;
            rec.h[cc] = half2_t{(_Float16)s[2 * c][cell],
                                (_Float16)s[2 * c + 1][cell]};
        }
        xt[((size_t)b * PLANE + cell0 + cell) * 4 + q] = *(const float4*)&rec;
    }
}

// ---------------------------------------------------------------------------
// Sort pass 2: exclusive scan over blocks for each bin, block-major layout.
// Each block handles 16 consecutive bins: LDS-transpose a 256x16 panel
// (coalesced loads/stores), wave w scans bin column w via __shfl_up.
// Grid = NBINS/16 = 128 blocks x 1024 threads.
// ---------------------------------------------------------------------------
__global__ __launch_bounds__(1024) void scan_bins(
    unsigned* __restrict__ blockHist, unsigned* __restrict__ binTotal)
{
    __shared__ unsigned sh[256][17];          // [sortblk][bin-in-group]+pad
    const int t    = threadIdx.x;
    const int bin0 = blockIdx.x * 16;
    const int col  = t & 15, row0 = t >> 4;   // 64 rows per pass
#pragma unroll
    for (int p = 0; p < 4; ++p) {
        const int row = row0 + p * 64;
        sh[row][col] = blockHist[(size_t)row * NBINS + bin0 + col];
    }
    __syncthreads();

    const int lane = t & 63, wave = t >> 6;   // wave w owns bin0+w
    unsigned v[4];
#pragma unroll
    for (int k = 0; k < 4; ++k) v[k] = sh[lane * 4 + k][wave];
    const unsigned tot = v[0] + v[1] + v[2] + v[3];
    unsigned s = tot;
#pragma unroll
    for (int d = 1; d < 64; d <<= 1) {
        const unsigned x = __shfl_up(s, d);
        if (lane >= d) s += x;
    }
    unsigned excl = s - tot;                  // prefix for lane's 4 rows
#pragma unroll
    for (int k = 0; k < 4; ++k) { const unsigned nv = excl; excl += v[k]; v[k] = nv; }
    __syncthreads();                          // reuse sh for writeback
#pragma unroll
    for (int k = 0; k < 4; ++k) sh[lane * 4 + k][wave] = v[k];
    if (lane == 63) binTotal[bin0 + wave] = s;
    __syncthreads();
#pragma unroll
    for (int p = 0; p < 4; ++p) {
        const int row = row0 + p * 64;
        blockHist[(size_t)row * NBINS + bin0 + col] = sh[row][col];
    }
}

// ---------------------------------------------------------------------------
// Sort pass 3: final positions. Wave-based scan of btot gives bin bases;
// the block's own blockHist row (exclusive prefix over blocks) is folded
// into bbs at preamble time, so the per-point lookup is LDS-only.
// Block 0 publishes pure bin bases to global bbase for interp. 1024 thr.
// ---------------------------------------------------------------------------
__global__ __launch_bounds__(1024) void scatter2(
    const float*    __restrict__ om,
    const unsigned* __restrict__ blockHist,
    const unsigned* __restrict__ btot,
    unsigned* __restrict__ bbase,
    unsigned* __restrict__ inv,
    float2* __restrict__ som)
{
    __shared__ unsigned h[NBINS];
    __shared__ unsigned bbs[NBINS];
    __shared__ unsigned wsum[16];
    const int t = threadIdx.x, blk = blockIdx.x;
    const int lane = t & 63, wave = t >> 6;

    // exclusive scan of btot -> bin bases: wave scan + 1-barrier fixup
    const unsigned v0 = btot[t * 2], v1 = btot[t * 2 + 1];
    const unsigned tot = v0 + v1;
    unsigned s = tot;
#pragma unroll
    for (int d = 1; d < 64; d <<= 1) {
        const unsigned x = __shfl_up(s, d);
        if (lane >= d) s += x;
    }
    if (lane == 63) wsum[wave] = s;
    // own row of scanned blockHist (coalesced 8 KB)
    const unsigned bh0 = blockHist[(size_t)blk * NBINS + t * 2];
    const unsigned bh1 = blockHist[(size_t)blk * NBINS + t * 2 + 1];
#pragma unroll
    for (int i = 0; i < NBINS / 1024; ++i) h[t + i * 1024] = 0u;
    __syncthreads();
    unsigned wp = 0;
#pragma unroll
    for (int i = 0; i < 16; ++i) wp += (i < wave) ? wsum[i] : 0u;
    const unsigned excl = wp + s - tot;
    bbs[t * 2]     = excl + bh0;              // binbase + row prefix folded
    bbs[t * 2 + 1] = excl + v0 + bh1;
    if (blk == 0) {                           // publish pure bases for interp
        bbase[t * 2]     = excl;
        bbase[t * 2 + 1] = excl + v0;
    }
    __syncthreads();

#pragma unroll
    for (int i = 0; i < PPB / 1024; ++i) {
        const int id = blk * PPB + i * 1024 + t;
        const int b = id >> 18, m = id & (KLEN - 1);
        const float om0 = om[(size_t)(b * 2 + 0) * KLEN + m];
        const float om1 = om[(size_t)(b * 2 + 1) * KLEN + m];
        const int g = (b << 10) | point_bin(om0, om1);
        const unsigned r = atomicAdd(&h[g], 1u);
        const unsigned pos = bbs[g] + r;       // LDS-only lookup
        inv[id]  = pos;                        // coalesced
        som[pos] = make_float2(om0, om1);      // scattered 8 B
    }
}

// ---------------------------------------------------------------------------
// Main interp: ONE BLOCK PER BIN, 512 threads. XCD-aware bin swizzle: each
// XCD owns 256 contiguous bins (8 tile rows) so neighboring bins' shared
// halo rows hit the local L2 instead of crossing XCDs. Stage the bin's
// 21x21 halo tile into LDS (proven TQ=5 record-pad layout). 2 LANES PER
// POINT, 8 coils each (even lane: slots {0,2}, odd: {1,3}). REAL-TABLE
// weights: w = c0r[j0]*c1r[j1]; each lane owns 3 j1 weights packed fp16x2,
// pair-shared via DPP. fdot2 with (w,0)/(0,w) is bit-identical to the
// complex path whose ci was exactly 0.
// ---------------------------------------------------------------------------
__global__ __launch_bounds__(512) void interp_bins(
    const float2*   __restrict__ som,
    const float*    __restrict__ t0,
    const float*    __restrict__ t1,
    const float4*   __restrict__ xt,
    const unsigned* __restrict__ bbase,
    float4*         __restrict__ osort)
{
    __shared__ float4 tile[TROWS * TROWS * TQ];   // 2205 f4 = 35280 B
    // XCD swizzle: blocks with the same (blockIdx & 7) land on one XCD
    // (round-robin dispatch); give each XCD a contiguous 256-bin range.
    const int bin = ((blockIdx.x & 7) << 8) | (blockIdx.x >> 3);
    const int t   = threadIdx.x;
    const int b   = bin >> 10;
    const int cx0 = ((bin >> 5) & 31) << 4;
    const int cy0 = (bin & 31) << 4;

    const unsigned p0  = bbase[bin];
    const unsigned p1e = (bin == NBINS - 1) ? (unsigned)NPTS : bbase[bin + 1];
    const int cnt = (int)(p1e - p0);

    // ---- stage halo tile: 441 records x 4 chunks, coalesced rows --------
    const float4* rec = xt + ((size_t)b << 20);   // b * PLANE * 4 chunks
    for (int f = t; f < TROWS * TROWS * 4; f += 512) {
        const int r = f >> 2, q = f & 3;
        const int row = r / TROWS;                // const-div -> magic mul
        const int col = r - row * TROWS;
        const int gr = (cx0 - 2 + row) & 511;
        const int gc = (cy0 - 2 + col) & 511;
        tile[r * TQ + q] = rec[(((size_t)((gr << 9) | gc)) << 2) + q];
    }
    __syncthreads();

    const int lane = t & 1;                    // pair lane
    for (int base = 0; base < cnt; base += 256) {
        const int idx = base + (t >> 1);
        if (idx >= cnt) continue;              // lane-pairs skip together
        const int pos = (int)p0 + idx;

        const float2 o = som[pos];
        const float om0 = o.x, om1 = o.y;

        const float TWO_PI = 6.2831853071795864769f;
        const float tm0 = (om0 * 512.0f) / TWO_PI;
        const float tm1 = (om1 * 512.0f) / TWO_PI;

        const float koff0 = 1.0f + floorf(tm0 - 3.0f);
        const float koff1 = 1.0f + floorf(tm1 - 3.0f);
        const int   k0    = (int)koff0;
        const int   k1    = (int)koff1;

        // c0: all 6 row weights, every lane. c1: this lane's 3 j1 weights.
        float c0r[6];
        int   loff[6];
#pragma unroll
        for (int j = 0; j < 6; ++j) {
            const float g0 = koff0 + (float)j;
            const int   d0 = (int)rintf((tm0 - g0) * 1024.0f) + TBL_CTR;
            c0r[j] = t0[d0];
            loff[j] = ((k1 + j - cy0 + 2) & 511) * TQ;   // in [0, 20]*TQ
        }
        const int j1o = 3 * lane;              // own j1 base: 0 or 3
        float c1r_[3];
#pragma unroll
        for (int k = 0; k < 3; ++k) {
            const int d1 = (int)rintf((tm1 - (koff1 + (float)(j1o + k))) * 1024.0f)
                           + TBL_CTR;
            c1r_[k] = t1[d1];
        }

        // acr[0..3]: slot (lane)   -> coils 4*lane   .. 4*lane+3
        // acr[4..7]: slot (lane+2) -> coils 4*lane+8 .. 4*lane+11
        float acr[8], aci[8];
#pragma unroll
        for (int c = 0; c < 8; ++c) { acr[c] = 0.f; aci[c] = 0.f; }

#define KB_DO_J1(JJ, P1, P2)                                                  \
        do {                                                                  \
            const half2_t p1 = (P1);                                          \
            const half2_t p2 = (P2);                                          \
            const float4 raw0 = rowp[loff[JJ]];                               \
            const float4 raw1 = rowp[loff[JJ] + 2];                           \
            const H8 v0 = *(const H8*)&raw0;                                  \
            const H8 v1 = *(const H8*)&raw1;                                  \
            _Pragma("unroll")                                                 \
            for (int cc = 0; cc < 4; ++cc) {                                  \
                acr[cc]   = __builtin_amdgcn_fdot2(v0.h[cc], p1, acr[cc],   false);\
                aci[cc]   = __builtin_amdgcn_fdot2(v0.h[cc], p2, aci[cc],   false);\
                acr[4+cc] = __builtin_amdgcn_fdot2(v1.h[cc], p1, acr[4+cc], false);\
                aci[4+cc] = __builtin_amdgcn_fdot2(v1.h[cc], p2, aci[4+cc], false);\
            }                                                                 \
        } while (0)

#pragma unroll
        for (int j0 = 0; j0 < 6; ++j0) {
            const int rIdx = (k0 + j0 - cx0 + 2) & 511;  // in [0, 20]
            const float4* rowp = &tile[rIdx * (TROWS * TQ) + lane];
            const float ar = c0r[j0];
            // this lane's 3 real weights, packed fp16x2 (RNE casts)
            const float wA = ar * c1r_[0];
            const float wB = ar * c1r_[1];
            const float wC = ar * c1r_[2];
            const half2_t pk01 = {(_Float16)wA, (_Float16)wB};
            const half2_t pk2  = {(_Float16)wC, (_Float16)0.0f};
            int i01, i2;
            __builtin_memcpy(&i01, &pk01, 4);
            __builtin_memcpy(&i2,  &pk2, 4);
            // pair-share: 4 DPP broadcasts cover all 6 j1 weights
            const int e01 = qbci<DPP_EVEN>(i01);
            const int e2  = qbci<DPP_EVEN>(i2);
            const int o01 = qbci<DPP_ODD >(i01);
            const int o2  = qbci<DPP_ODD >(i2);

            // j1 slot weights: (w,0) for re-acc, (0,w) for im-acc
            KB_DO_J1(0, h2bits(e01 & 0xffff),       h2bits(e01 << 16));
            KB_DO_J1(1, h2bits((int)((unsigned)e01 >> 16)), h2bits(e01 & (int)0xffff0000u));
            KB_DO_J1(2, h2bits(e2 & 0xffff),        h2bits(e2 << 16));
            KB_DO_J1(3, h2bits(o01 & 0xffff),       h2bits(o01 << 16));
            KB_DO_J1(4, h2bits((int)((unsigned)o01 >> 16)), h2bits(o01 & (int)0xffff0000u));
            KB_DO_J1(5, h2bits(o2 & 0xffff),        h2bits(o2 << 16));
        }
#undef KB_DO_J1

        // phase twist: exp(i * (om0+om1)*128); |ph| <= 128 rev -> native ok
        const float ph = om0 * 128.0f + om1 * 128.0f;
        const float s = __sinf(ph), c = __cosf(ph);

        // even lane writes slots 0,2; odd writes 1,3 (per-instr consecutive)
        float4* op = osort + (size_t)pos * 4 + lane;
#pragma unroll
        for (int q = 0; q < 2; ++q) {
            H8 outrec;
#pragma unroll
            for (int cc = 0; cc < 4; ++cc) {
                const int a = q * 4 + cc;
                const float yr = acr[a] * c - aci[a] * s;
                const float yi = acr[a] * s + aci[a] * c;
                outrec.h[cc] = half2_t{(_Float16)yr, (_Float16)yi};
            }
            op[q * 2] = *(const float4*)&outrec;
        }
    }
}

// ---------------------------------------------------------------------------
// Unsort: thread per point id; gather 64 B record from osort, store coalesced
// into final (b,c,ri,m) layout. 1024 threads for gather-latency hiding.
// ---------------------------------------------------------------------------
__global__ __launch_bounds__(1024) void unsort_kernel(
    const unsigned* __restrict__ inv,
    const float4*   __restrict__ osort,
    float*          __restrict__ out)
{
    const int id = blockIdx.x * blockDim.x + threadIdx.x;   // [0, NPTS)
    const int b = id >> 18, m = id & (KLEN - 1);
    const unsigned pos = inv[id];
    const float4* rp = osort + (size_t)pos * 4;

    float4 raw[4];
#pragma unroll
    for (int q = 0; q < 4; ++q) raw[q] = rp[q];

    float* ob = out + (size_t)b * NCOILS * 2 * KLEN + m;
#pragma unroll
    for (int q = 0; q < 4; ++q) {
        const H8 v = *(const H8*)&raw[q];
#pragma unroll
        for (int cc = 0; cc < 4; ++cc) {
            const int coil = q * 4 + cc;
            ob[(size_t)(2 * coil)     * KLEN] = (float)v.h[cc].x;
            ob[(size_t)(2 * coil + 1) * KLEN] = (float)v.h[cc].y;
        }
    }
}

// ---------------------------------------------------------------------------
// Middle path (ws >= xt only): direct-order interp (4 lanes/point).
// Keeps the general complex-table math (not perf-critical).
// ---------------------------------------------------------------------------
__global__ __launch_bounds__(256) void interp_direct(
    const float*  __restrict__ om,
    const float*  __restrict__ t0,
    const float*  __restrict__ t1,
    const float4* __restrict__ xt,
    float*        __restrict__ out)
{
    const int tid  = blockIdx.x * blockDim.x + threadIdx.x;
    const int lane = tid & 3;
    const int p    = tid >> 2;
    const int b    = p >> 18;
    const int m    = p & (KLEN - 1);

    const float om0 = om[(size_t)(b * 2 + 0) * KLEN + m];
    const float om1 = om[(size_t)(b * 2 + 1) * KLEN + m];

    const float TWO_PI = 6.2831853071795864769f;
    const float tm0 = (om0 * 512.0f) / TWO_PI;
    const float tm1 = (om1 * 512.0f) / TWO_PI;
    const float koff0 = 1.0f + floorf(tm0 - 3.0f);
    const float koff1 = 1.0f + floorf(tm1 - 3.0f);
    const int k0 = (int)koff0, k1 = (int)koff1;

    float c0r[6], c0i[6], c1r[6], c1i[6];
    int coff[6];
#pragma unroll
    for (int j = 0; j < 6; ++j) {
        const float g0 = koff0 + (float)j;
        const int d0 = (int)rintf((tm0 - g0) * 1024.0f) + TBL_CTR;
        c0r[j] = t0[d0];
        c0i[j] = t0[TBL_LEN + d0];
        const float g1 = koff1 + (float)j;
        const int d1 = (int)rintf((tm1 - g1) * 1024.0f) + TBL_CTR;
        c1r[j] = t1[d1];
        c1i[j] = t1[TBL_LEN + d1];
        coff[j] = ((k1 + j) & 511) << 2;
    }

    const float4* rec = xt + ((size_t)b << 20);
    float acr[4] = {0.f, 0.f, 0.f, 0.f};
    float aci[4] = {0.f, 0.f, 0.f, 0.f};
#pragma unroll
    for (int j0 = 0; j0 < 6; ++j0) {
        const int roff = (k0 + j0) & 511;
        const float4* rowp = rec + ((size_t)roff << 11) + lane;
        const float ar = c0r[j0], ai = c0i[j0];
#pragma unroll
        for (int j1 = 0; j1 < 6; ++j1) {
            const float br = c1r[j1], bi = c1i[j1];
            const float cr = ar * br - ai * bi;
            const float ci = ar * bi + ai * br;
            const half2_t p1 = {(_Float16)cr, (_Float16)(-ci)};
            const half2_t p2 = {(_Float16)ci, (_Float16)cr};
            const float4 raw = rowp[coff[j1]];
            const H8 v = *(const H8*)&raw;
#pragma unroll
            for (int cc = 0; cc < 4; ++cc) {
                acr[cc] = __builtin_amdgcn_fdot2(v.h[cc], p1, acr[cc], false);
                aci[cc] = __builtin_amdgcn_fdot2(v.h[cc], p2, aci[cc], false);
            }
        }
    }

    const float ph = om0 * 128.0f + om1 * 128.0f;
    const float s = sinf(ph), c = cosf(ph);
#pragma unroll
    for (int cc = 0; cc < 4; ++cc) {
        const float yr = acr[cc] * c - aci[cc] * s;
        const float yi = acr[cc] * s + aci[cc] * c;
        const int coil = lane * 4 + cc;
        const size_t ob = ((size_t)(b * NCOILS + coil) * 2) * KLEN + m;
        out[ob]        = yr;
        out[ob + KLEN] = yi;
    }
}

// ---------------------------------------------------------------------------
// Fallback (tiny ws): one thread per point, original layout. General math.
// ---------------------------------------------------------------------------
__global__ __launch_bounds__(256) void interp_fallback(
    const float* __restrict__ om,
    const float* __restrict__ t0,
    const float* __restrict__ t1,
    const float* __restrict__ x,
    float*       __restrict__ out)
{
    const int p = blockIdx.x * blockDim.x + threadIdx.x;
    const int b = p >> 18;
    const int m = p & (KLEN - 1);

    const float om0 = om[(size_t)(b * 2 + 0) * KLEN + m];
    const float om1 = om[(size_t)(b * 2 + 1) * KLEN + m];
    const float TWO_PI = 6.2831853071795864769f;
    const float tm0 = (om0 * 512.0f) / TWO_PI;
    const float tm1 = (om1 * 512.0f) / TWO_PI;
    const float koff0 = 1.0f + floorf(tm0 - 3.0f);
    const float koff1 = 1.0f + floorf(tm1 - 3.0f);
    const int k0 = (int)koff0, k1 = (int)koff1;

    float c0r[6], c0i[6], c1r[6], c1i[6];
    int roff[6], coff[6];
#pragma unroll
    for (int j = 0; j < 6; ++j) {
        const float g0 = koff0 + (float)j;
        const int d0 = (int)rintf((tm0 - g0) * 1024.0f) + TBL_CTR;
        c0r[j] = t0[d0];
        c0i[j] = t0[TBL_LEN + d0];
        const float g1 = koff1 + (float)j;
        const int d1 = (int)rintf((tm1 - g1) * 1024.0f) + TBL_CTR;
        c1r[j] = t1[d1];
        c1i[j] = t1[TBL_LEN + d1];
        roff[j] = (k0 + j) & 511;
        coff[j] = (k1 + j) & 511;
    }

    float accr[NCOILS], acci[NCOILS];
#pragma unroll
    for (int c = 0; c < NCOILS; ++c) { accr[c] = 0.f; acci[c] = 0.f; }

    const float* xb = x + (size_t)b * NCOILS * 2 * PLANE;
#pragma unroll
    for (int j0 = 0; j0 < 6; ++j0) {
        const float ar = c0r[j0], ai = c0i[j0];
        const int rb = roff[j0] * GY;
#pragma unroll
        for (int j1 = 0; j1 < 6; ++j1) {
            const float br = c1r[j1], bi = c1i[j1];
            const float cr = ar * br - ai * bi;
            const float ci = ar * bi + ai * br;
            const int ai_idx = rb + coff[j1];
#pragma unroll
            for (int c = 0; c < NCOILS; ++c) {
                const float dr = xb[(size_t)c * (2 * PLANE) + ai_idx];
                const float di = xb[(size_t)c * (2 * PLANE) + PLANE + ai_idx];
                accr[c] += cr * dr - ci * di;
                acci[c] += cr * di + ci * dr;
            }
        }
    }

    const float ph = om0 * 128.0f + om1 * 128.0f;
    const float s = sinf(ph), c = cosf(ph);
#pragma unroll
    for (int cc = 0; cc < NCOILS; ++cc) {
        const float yr = accr[cc] * c - acci[cc] * s;
        const float yi = accr[cc] * s + acci[cc] * c;
        size_t ob = ((size_t)(b * NCOILS + cc) * 2) * KLEN + m;
        out[ob]        = yr;
        out[ob + KLEN] = yi;
    }
}

extern "C" void kernel_launch(void* const* d_in, const int* in_sizes, int n_in,
                              void* d_out, int out_size, void* d_ws, size_t ws_size,
                              hipStream_t stream)
{
    const float* x  = (const float*)d_in[0];
    const float* om = (const float*)d_in[1];
    const float* t0 = (const float*)d_in[2];
    const float* t1 = (const float*)d_in[3];
    float* out = (float*)d_out;

    char* ws = (char*)d_ws;
    const size_t xt_bytes = (size_t)NBATCH * PLANE * NCOILS * 2 * sizeof(__half);

    if (ws_size >= (size_t)WS_TOTAL) {
        float4*   xt     = (float4*)(ws + WS_XT);
        float4*   osort  = (float4*)(ws + WS_OSORT);
        unsigned* bhist  = (unsigned*)(ws + WS_BHIST);
        unsigned* btot   = (unsigned*)(ws + WS_BTOT);
        unsigned* bbase  = (unsigned*)(ws + WS_BBASE);
        unsigned* inv    = (unsigned*)(ws + WS_INV);
        float2*   som    = (float2*)(ws + WS_SOM);

        transpose_hist<<<TBLKS + NBLK, 256, 0, stream>>>(x, xt, om, bhist);
        scan_bins<<<NBINS / 16, 1024, 0, stream>>>(bhist, btot);
        scatter2<<<NBLK, 1024, 0, stream>>>(om, bhist, btot, bbase, inv, som);
        interp_bins<<<NBINS, 512, 0, stream>>>(som, t0, t1, xt, bbase, osort);
        unsort_kernel<<<NPTS / 1024, 1024, 0, stream>>>(inv, osort, out);
    } else if (ws_size >= xt_bytes) {
        float4* xt = (float4*)ws;
        transpose_hist<<<TBLKS, 256, 0, stream>>>(x, xt, om, nullptr);
        interp_direct<<<NPTS * 4 / 256, 256, 0, stream>>>(om, t0, t1, xt, out);
    } else {
        interp_fallback<<<NPTS / 256, 256, 0, stream>>>(om, t0, t1, x, out);
    }
}

// Round 16
// 188.273 us; speedup vs baseline: 1.0234x; 1.0160x over previous
//
#include <hip/hip_runtime.h>
#include <hip/hip_fp16.h>

// KbInterpForw: table-based KB NUFFT interpolation, forward.
// x: (2,16,2,512,512) f32, om: (2,2,262144) f32, tables: (2,6145) f32 each.
// out: (2,16,2,262144) f32.
//
// R22 (on R21's 191.3 us):
//  - R16's write-side-scatter idea done right: som[] and inv[] DELETED;
//    the only per-point sort artifact is fwd[pos]=id (scattered 4 B, same
//    cache-line count as the old scattered 8 B som write -> no added cost,
//    and the coalesced inv write/read round-trip disappears).
//  - interp reads fwd[pos] coalesced, recovers m = id&(KLEN-1) (b known
//    from the bin), gathers om0/om1 (2x 4 B over a 2 MB L2-hot region,
//    hidden by 32 waves), and writes its record to osort[id] -- scattered
//    FULL-LINE 64 B stores (R16 measured ~free).
//  - unsort is now PURE STREAMING: coalesced osort[id] read + coalesced
//    out writes. The 33 MB random gather is gone (~-9 us).
//  - Frozen: R19 sort layout, R21 XCD bin swizzle, TQ=5 tile, 2-lane
//    real-weight DPP interp.

#define KLEN      262144      // 2^18
#define GX        512
#define GY        512
#define NCOILS    16
#define NBATCH    2
#define TBL_LEN   6145        // 6*1024+1
#define TBL_CTR   3072
#define PLANE     (GX*GY)
#define NPTS      (NBATCH*KLEN)
#define NBINS     2048        // NBATCH * 32*32 tiles
#define NBLK      256         // sort blocks
#define PPB       2048        // points per sort block (NPTS/NBLK)
#define TBLKS     (NBATCH*PLANE/256)   // 8192 transpose blocks

#define TROWS     21          // 16 + 5 halo
#define TQ        5           // float4 slots per record in LDS (4 used + 1 pad)

typedef _Float16 half2_t __attribute__((ext_vector_type(2)));
struct alignas(16) H8 { half2_t h[4]; };   // 4 coils' (re,im) fp16 = 16 B

// ---------------------------------------------------------------------------
// ws layout (bytes). blockHist/btot alias the osort region (dead before
// interp writes osort). bbase and fwd live OUTSIDE osort: both are read by
// interp while osort is being written.
// ---------------------------------------------------------------------------
#define WS_XT       0                         // 33554432  fp16 grid records
#define WS_OSORT    33554432                  // 33554432  fp16 outputs (id-ordered)
#define WS_BHIST    33554432                  //  2097152  u32 [NBLK][NBINS] (alias osort)
#define WS_BTOT     (33554432+2097152)        //     8192  u32 [NBINS]      (alias osort)
#define WS_BBASE    67108864                  //     8192  u32 [NBINS]  NOT aliased
#define WS_FWD      (67108864+8192)           //  2097152  u32 id per sorted pos
#define WS_TOTAL    75497472

__device__ inline int point_bin(float om0, float om1)
{
    const float TWO_PI = 6.2831853071795864769f;
    const float tm0 = (om0 * 512.0f) / TWO_PI;
    const float tm1 = (om1 * 512.0f) / TWO_PI;
    const int cx = ((int)floorf(tm0)) & 511;
    const int cy = ((int)floorf(tm1)) & 511;
    return ((cx >> 4) << 5) | (cy >> 4);      // [0, 1024)
}

// quad-perm broadcast of a 32-bit value with explicit control byte. VALU op.
// Sources must be active lanes (we only reference the reader's own pair).
template<int CTRL>
__device__ inline int qbci(int i)
{
    return __builtin_amdgcn_mov_dpp(i, CTRL, 0xf, 0xf, true);
}
#define DPP_EVEN 0xA0   // [0,0,2,2]: read even lane of own pair
#define DPP_ODD  0xF5   // [1,1,3,3]: read odd lane of own pair

__device__ inline half2_t h2bits(int i)
{
    half2_t r;
    __builtin_memcpy(&r, &i, 4);
    return r;
}

// ---------------------------------------------------------------------------
// Fused transpose+hist. Blocks [0, TBLKS): transpose 256 consecutive cells
// via LDS. Blocks [TBLKS, TBLKS+NBLK): per-block LDS histogram ->
// blockHist[blk][NBINS] (block-major, coalesced writeout). Pass
// blockHist=nullptr (grid=TBLKS) to run transpose only (middle path).
// ---------------------------------------------------------------------------
__global__ __launch_bounds__(256) void transpose_hist(
    const float* __restrict__ x, float4* __restrict__ xt,
    const float* __restrict__ om, unsigned* __restrict__ blockHist)
{
    __shared__ float s[32][260];   // 33280 B; hist aliases first 8192 B
    const int t = threadIdx.x;

    if (blockHist != nullptr && blockIdx.x >= TBLKS) {
        // ---- histogram body (256 threads, 8 iters) ----------------------
        unsigned* h = (unsigned*)s;               // [NBINS]
        const int blk = blockIdx.x - TBLKS;
#pragma unroll
        for (int i = 0; i < NBINS / 256; ++i) h[t + i * 256] = 0u;
        __syncthreads();
#pragma unroll
        for (int i = 0; i < PPB / 256; ++i) {
            const int id = blk * PPB + i * 256 + t;
            const int b = id >> 18, m = id & (KLEN - 1);
            const float om0 = om[(size_t)(b * 2 + 0) * KLEN + m];
            const float om1 = om[(size_t)(b * 2 + 1) * KLEN + m];
            const int g = (b << 10) | point_bin(om0, om1);
            atomicAdd(&h[g], 1u);
        }
        __syncthreads();
#pragma unroll
        for (int i = 0; i < NBINS / 256; ++i) {
            const int bin = t + i * 256;
            blockHist[(size_t)blk * NBINS + bin] = h[bin];   // coalesced row
        }
        return;
    }

    // ---- transpose body -------------------------------------------------
    const int blk   = blockIdx.x;            // [0, TBLKS)
    const int base  = blk * 256;
    const int b     = base >> 18;
    const int cell0 = base & (PLANE - 1);

    const float* xb = x + (size_t)b * 32 * PLANE + cell0;
#pragma unroll
    for (int i = 0; i < 8; ++i) {
        const int fidx = i * 256 + t;        // [0, 2048)
        const int pl = fidx >> 6;            // wave-uniform plane
        const int j  = fidx & 63;
        const float4 v = *(const float4*)(xb + (size_t)pl * PLANE + j * 4);
        *(float4*)&s[pl][j * 4] = v;
    }
    __syncthreads();
#pragma unroll
    for (int i = 0; i < 4; ++i) {
        const int chunk = i * 256 + t;       // [0, 1024)
        const int cell = chunk >> 2, q = chunk & 3;
        H8 rec;
#pragma unroll
        for (int cc = 0; cc < 4; ++cc) {
            const int c = q * 4 + cc;
            rec.h[cc] = half2_t{(_Float16)s[2 * c][cell],
                                (_Float16)s[2 * c + 1][cell]};
        }
        xt[((size_t)b * PLANE + cell0 + cell) * 4 + q] = *(const float4*)&rec;
    }
}

// ---------------------------------------------------------------------------
// Sort pass 2: exclusive scan over blocks for each bin, block-major layout.
// Each block handles 16 consecutive bins: LDS-transpose a 256x16 panel
// (coalesced loads/stores), wave w scans bin column w via __shfl_up.
// Grid = NBINS/16 = 128 blocks x 1024 threads.
// ---------------------------------------------------------------------------
__global__ __launch_bounds__(1024) void scan_bins(
    unsigned* __restrict__ blockHist, unsigned* __restrict__ binTotal)
{
    __shared__ unsigned sh[256][17];          // [sortblk][bin-in-group]+pad
    const int t    = threadIdx.x;
    const int bin0 = blockIdx.x * 16;
    const int col  = t & 15, row0 = t >> 4;   // 64 rows per pass
#pragma unroll
    for (int p = 0; p < 4; ++p) {
        const int row = row0 + p * 64;
        sh[row][col] = blockHist[(size_t)row * NBINS + bin0 + col];
    }
    __syncthreads();

    const int lane = t & 63, wave = t >> 6;   // wave w owns bin0+w
    unsigned v[4];
#pragma unroll
    for (int k = 0; k < 4; ++k) v[k] = sh[lane * 4 + k][wave];
    const unsigned tot = v[0] + v[1] + v[2] + v[3];
    unsigned s = tot;
#pragma unroll
    for (int d = 1; d < 64; d <<= 1) {
        const unsigned x = __shfl_up(s, d);
        if (lane >= d) s += x;
    }
    unsigned excl = s - tot;                  // prefix for lane's 4 rows
#pragma unroll
    for (int k = 0; k < 4; ++k) { const unsigned nv = excl; excl += v[k]; v[k] = nv; }
    __syncthreads();                          // reuse sh for writeback
#pragma unroll
    for (int k = 0; k < 4; ++k) sh[lane * 4 + k][wave] = v[k];
    if (lane == 63) binTotal[bin0 + wave] = s;
    __syncthreads();
#pragma unroll
    for (int p = 0; p < 4; ++p) {
        const int row = row0 + p * 64;
        blockHist[(size_t)row * NBINS + bin0 + col] = sh[row][col];
    }
}

// ---------------------------------------------------------------------------
// Sort pass 3: final positions. Wave-based scan of btot gives bin bases;
// the block's own blockHist row (exclusive prefix over blocks) is folded
// into bbs at preamble time, so the per-point lookup is LDS-only.
// Writes ONLY fwd[pos]=id (scattered 4 B). Block 0 publishes pure bin
// bases to global bbase for interp. 1024 threads.
// ---------------------------------------------------------------------------
__global__ __launch_bounds__(1024) void scatter2(
    const float*    __restrict__ om,
    const unsigned* __restrict__ blockHist,
    const unsigned* __restrict__ btot,
    unsigned* __restrict__ bbase,
    unsigned* __restrict__ fwd)
{
    __shared__ unsigned h[NBINS];
    __shared__ unsigned bbs[NBINS];
    __shared__ unsigned wsum[16];
    const int t = threadIdx.x, blk = blockIdx.x;
    const int lane = t & 63, wave = t >> 6;

    // exclusive scan of btot -> bin bases: wave scan + 1-barrier fixup
    const unsigned v0 = btot[t * 2], v1 = btot[t * 2 + 1];
    const unsigned tot = v0 + v1;
    unsigned s = tot;
#pragma unroll
    for (int d = 1; d < 64; d <<= 1) {
        const unsigned x = __shfl_up(s, d);
        if (lane >= d) s += x;
    }
    if (lane == 63) wsum[wave] = s;
    // own row of scanned blockHist (coalesced 8 KB)
    const unsigned bh0 = blockHist[(size_t)blk * NBINS + t * 2];
    const unsigned bh1 = blockHist[(size_t)blk * NBINS + t * 2 + 1];
#pragma unroll
    for (int i = 0; i < NBINS / 1024; ++i) h[t + i * 1024] = 0u;
    __syncthreads();
    unsigned wp = 0;
#pragma unroll
    for (int i = 0; i < 16; ++i) wp += (i < wave) ? wsum[i] : 0u;
    const unsigned excl = wp + s - tot;
    bbs[t * 2]     = excl + bh0;              // binbase + row prefix folded
    bbs[t * 2 + 1] = excl + v0 + bh1;
    if (blk == 0) {                           // publish pure bases for interp
        bbase[t * 2]     = excl;
        bbase[t * 2 + 1] = excl + v0;
    }
    __syncthreads();

#pragma unroll
    for (int i = 0; i < PPB / 1024; ++i) {
        const int id = blk * PPB + i * 1024 + t;
        const int b = id >> 18, m = id & (KLEN - 1);
        const float om0 = om[(size_t)(b * 2 + 0) * KLEN + m];
        const float om1 = om[(size_t)(b * 2 + 1) * KLEN + m];
        const int g = (b << 10) | point_bin(om0, om1);
        const unsigned r = atomicAdd(&h[g], 1u);
        const unsigned pos = bbs[g] + r;       // LDS-only lookup
        fwd[pos] = (unsigned)id;               // scattered 4 B (only artifact)
    }
}

// ---------------------------------------------------------------------------
// Main interp: ONE BLOCK PER BIN, 512 threads, XCD-aware bin swizzle. Reads
// fwd[pos] coalesced, recovers m (b known from bin), gathers om0/om1 from
// the L2-hot om planes. Stage the bin's 21x21 halo tile into LDS (proven
// TQ=5 record-pad layout). 2 LANES PER POINT, 8 coils each; REAL-TABLE
// weights, DPP pair-share. Output record written to osort[id] (id-ordered,
// scattered full-line 64 B stores) so unsort is pure streaming.
// ---------------------------------------------------------------------------
__global__ __launch_bounds__(512) void interp_bins(
    const float*    __restrict__ om,
    const float*    __restrict__ t0,
    const float*    __restrict__ t1,
    const float4*   __restrict__ xt,
    const unsigned* __restrict__ bbase,
    const unsigned* __restrict__ fwd,
    float4*         __restrict__ osort)
{
    __shared__ float4 tile[TROWS * TROWS * TQ];   // 2205 f4 = 35280 B
    // XCD swizzle: round-robin dispatch puts (blockIdx & 7) on one XCD;
    // give each XCD a contiguous 256-bin range (8 tile rows).
    const int bin = ((blockIdx.x & 7) << 8) | (blockIdx.x >> 3);
    const int t   = threadIdx.x;
    const int b   = bin >> 10;
    const int cx0 = ((bin >> 5) & 31) << 4;
    const int cy0 = (bin & 31) << 4;

    const unsigned p0  = bbase[bin];
    const unsigned p1e = (bin == NBINS - 1) ? (unsigned)NPTS : bbase[bin + 1];
    const int cnt = (int)(p1e - p0);

    // ---- stage halo tile: 441 records x 4 chunks, coalesced rows --------
    const float4* rec = xt + ((size_t)b << 20);   // b * PLANE * 4 chunks
    for (int f = t; f < TROWS * TROWS * 4; f += 512) {
        const int r = f >> 2, q = f & 3;
        const int row = r / TROWS;                // const-div -> magic mul
        const int col = r - row * TROWS;
        const int gr = (cx0 - 2 + row) & 511;
        const int gc = (cy0 - 2 + col) & 511;
        tile[r * TQ + q] = rec[(((size_t)((gr << 9) | gc)) << 2) + q];
    }
    __syncthreads();

    const float* omb0 = om + (size_t)(b * 2 + 0) * KLEN;
    const float* omb1 = om + (size_t)(b * 2 + 1) * KLEN;

    const int lane = t & 1;                    // pair lane
    for (int base = 0; base < cnt; base += 256) {
        const int idx = base + (t >> 1);
        if (idx >= cnt) continue;              // lane-pairs skip together
        const int pos = (int)p0 + idx;

        const unsigned oid = fwd[pos];         // coalesced
        const int m = (int)(oid & (KLEN - 1));
        const float om0 = omb0[m];             // L2-hot gather
        const float om1 = omb1[m];

        const float TWO_PI = 6.2831853071795864769f;
        const float tm0 = (om0 * 512.0f) / TWO_PI;
        const float tm1 = (om1 * 512.0f) / TWO_PI;

        const float koff0 = 1.0f + floorf(tm0 - 3.0f);
        const float koff1 = 1.0f + floorf(tm1 - 3.0f);
        const int   k0    = (int)koff0;
        const int   k1    = (int)koff1;

        // c0: all 6 row weights, every lane. c1: this lane's 3 j1 weights.
        float c0r[6];
        int   loff[6];
#pragma unroll
        for (int j = 0; j < 6; ++j) {
            const float g0 = koff0 + (float)j;
            const int   d0 = (int)rintf((tm0 - g0) * 1024.0f) + TBL_CTR;
            c0r[j] = t0[d0];
            loff[j] = ((k1 + j - cy0 + 2) & 511) * TQ;   // in [0, 20]*TQ
        }
        const int j1o = 3 * lane;              // own j1 base: 0 or 3
        float c1r_[3];
#pragma unroll
        for (int k = 0; k < 3; ++k) {
            const int d1 = (int)rintf((tm1 - (koff1 + (float)(j1o + k))) * 1024.0f)
                           + TBL_CTR;
            c1r_[k] = t1[d1];
        }

        // acr[0..3]: slot (lane)   -> coils 4*lane   .. 4*lane+3
        // acr[4..7]: slot (lane+2) -> coils 4*lane+8 .. 4*lane+11
        float acr[8], aci[8];
#pragma unroll
        for (int c = 0; c < 8; ++c) { acr[c] = 0.f; aci[c] = 0.f; }

#define KB_DO_J1(JJ, P1, P2)                                                  \
        do {                                                                  \
            const half2_t p1 = (P1);                                          \
            const half2_t p2 = (P2);                                          \
            const float4 raw0 = rowp[loff[JJ]];                               \
            const float4 raw1 = rowp[loff[JJ] + 2];                           \
            const H8 v0 = *(const H8*)&raw0;                                  \
            const H8 v1 = *(const H8*)&raw1;                                  \
            _Pragma("unroll")                                                 \
            for (int cc = 0; cc < 4; ++cc) {                                  \
                acr[cc]   = __builtin_amdgcn_fdot2(v0.h[cc], p1, acr[cc],   false);\
                aci[cc]   = __builtin_amdgcn_fdot2(v0.h[cc], p2, aci[cc],   false);\
                acr[4+cc] = __builtin_amdgcn_fdot2(v1.h[cc], p1, acr[4+cc], false);\
                aci[4+cc] = __builtin_amdgcn_fdot2(v1.h[cc], p2, aci[4+cc], false);\
            }                                                                 \
        } while (0)

#pragma unroll
        for (int j0 = 0; j0 < 6; ++j0) {
            const int rIdx = (k0 + j0 - cx0 + 2) & 511;  // in [0, 20]
            const float4* rowp = &tile[rIdx * (TROWS * TQ) + lane];
            const float ar = c0r[j0];
            // this lane's 3 real weights, packed fp16x2 (RNE casts)
            const float wA = ar * c1r_[0];
            const float wB = ar * c1r_[1];
            const float wC = ar * c1r_[2];
            const half2_t pk01 = {(_Float16)wA, (_Float16)wB};
            const half2_t pk2  = {(_Float16)wC, (_Float16)0.0f};
            int i01, i2;
            __builtin_memcpy(&i01, &pk01, 4);
            __builtin_memcpy(&i2,  &pk2, 4);
            // pair-share: 4 DPP broadcasts cover all 6 j1 weights
            const int e01 = qbci<DPP_EVEN>(i01);
            const int e2  = qbci<DPP_EVEN>(i2);
            const int o01 = qbci<DPP_ODD >(i01);
            const int o2  = qbci<DPP_ODD >(i2);

            // j1 slot weights: (w,0) for re-acc, (0,w) for im-acc
            KB_DO_J1(0, h2bits(e01 & 0xffff),       h2bits(e01 << 16));
            KB_DO_J1(1, h2bits((int)((unsigned)e01 >> 16)), h2bits(e01 & (int)0xffff0000u));
            KB_DO_J1(2, h2bits(e2 & 0xffff),        h2bits(e2 << 16));
            KB_DO_J1(3, h2bits(o01 & 0xffff),       h2bits(o01 << 16));
            KB_DO_J1(4, h2bits((int)((unsigned)o01 >> 16)), h2bits(o01 & (int)0xffff0000u));
            KB_DO_J1(5, h2bits(o2 & 0xffff),        h2bits(o2 << 16));
        }
#undef KB_DO_J1

        // phase twist: exp(i * (om0+om1)*128); |ph| <= 128 rev -> native ok
        const float ph = om0 * 128.0f + om1 * 128.0f;
        const float s = __sinf(ph), c = __cosf(ph);

        // id-ordered output: the lane pair covers one full 64 B line
        float4* op = osort + (size_t)oid * 4 + lane;
#pragma unroll
        for (int q = 0; q < 2; ++q) {
            H8 outrec;
#pragma unroll
            for (int cc = 0; cc < 4; ++cc) {
                const int a = q * 4 + cc;
                const float yr = acr[a] * c - aci[a] * s;
                const float yi = acr[a] * s + aci[a] * c;
                outrec.h[cc] = half2_t{(_Float16)yr, (_Float16)yi};
            }
            op[q * 2] = *(const float4*)&outrec;
        }
    }
}

// ---------------------------------------------------------------------------
// Unsort: PURE STREAMING. osort is id-ordered: thread id reads its 64 B
// record coalesced and stores coalesced into the final (b,c,ri,m) layout.
// ---------------------------------------------------------------------------
__global__ __launch_bounds__(1024) void unsort_kernel(
    const float4*   __restrict__ osort,
    float*          __restrict__ out)
{
    const int id = blockIdx.x * blockDim.x + threadIdx.x;   // [0, NPTS)
    const int b = id >> 18, m = id & (KLEN - 1);
    const float4* rp = osort + (size_t)id * 4;

    float4 raw[4];
#pragma unroll
    for (int q = 0; q < 4; ++q) raw[q] = rp[q];

    float* ob = out + (size_t)b * NCOILS * 2 * KLEN + m;
#pragma unroll
    for (int q = 0; q < 4; ++q) {
        const H8 v = *(const H8*)&raw[q];
#pragma unroll
        for (int cc = 0; cc < 4; ++cc) {
            const int coil = q * 4 + cc;
            ob[(size_t)(2 * coil)     * KLEN] = (float)v.h[cc].x;
            ob[(size_t)(2 * coil + 1) * KLEN] = (float)v.h[cc].y;
        }
    }
}

// ---------------------------------------------------------------------------
// Middle path (ws >= xt only): direct-order interp (4 lanes/point).
// Keeps the general complex-table math (not perf-critical).
// ---------------------------------------------------------------------------
__global__ __launch_bounds__(256) void interp_direct(
    const float*  __restrict__ om,
    const float*  __restrict__ t0,
    const float*  __restrict__ t1,
    const float4* __restrict__ xt,
    float*        __restrict__ out)
{
    const int tid  = blockIdx.x * blockDim.x + threadIdx.x;
    const int lane = tid & 3;
    const int p    = tid >> 2;
    const int b    = p >> 18;
    const int m    = p & (KLEN - 1);

    const float om0 = om[(size_t)(b * 2 + 0) * KLEN + m];
    const float om1 = om[(size_t)(b * 2 + 1) * KLEN + m];

    const float TWO_PI = 6.2831853071795864769f;
    const float tm0 = (om0 * 512.0f) / TWO_PI;
    const float tm1 = (om1 * 512.0f) / TWO_PI;
    const float koff0 = 1.0f + floorf(tm0 - 3.0f);
    const float koff1 = 1.0f + floorf(tm1 - 3.0f);
    const int k0 = (int)koff0, k1 = (int)koff1;

    float c0r[6], c0i[6], c1r[6], c1i[6];
    int coff[6];
#pragma unroll
    for (int j = 0; j < 6; ++j) {
        const float g0 = koff0 + (float)j;
        const int d0 = (int)rintf((tm0 - g0) * 1024.0f) + TBL_CTR;
        c0r[j] = t0[d0];
        c0i[j] = t0[TBL_LEN + d0];
        const float g1 = koff1 + (float)j;
        const int d1 = (int)rintf((tm1 - g1) * 1024.0f) + TBL_CTR;
        c1r[j] = t1[d1];
        c1i[j] = t1[TBL_LEN + d1];
        coff[j] = ((k1 + j) & 511) << 2;
    }

    const float4* rec = xt + ((size_t)b << 20);
    float acr[4] = {0.f, 0.f, 0.f, 0.f};
    float aci[4] = {0.f, 0.f, 0.f, 0.f};
#pragma unroll
    for (int j0 = 0; j0 < 6; ++j0) {
        const int roff = (k0 + j0) & 511;
        const float4* rowp = rec + ((size_t)roff << 11) + lane;
        const float ar = c0r[j0], ai = c0i[j0];
#pragma unroll
        for (int j1 = 0; j1 < 6; ++j1) {
            const float br = c1r[j1], bi = c1i[j1];
            const float cr = ar * br - ai * bi;
            const float ci = ar * bi + ai * br;
            const half2_t p1 = {(_Float16)cr, (_Float16)(-ci)};
            const half2_t p2 = {(_Float16)ci, (_Float16)cr};
            const float4 raw = rowp[coff[j1]];
            const H8 v = *(const H8*)&raw;
#pragma unroll
            for (int cc = 0; cc < 4; ++cc) {
                acr[cc] = __builtin_amdgcn_fdot2(v.h[cc], p1, acr[cc], false);
                aci[cc] = __builtin_amdgcn_fdot2(v.h[cc], p2, aci[cc], false);
            }
        }
    }

    const float ph = om0 * 128.0f + om1 * 128.0f;
    const float s = sinf(ph), c = cosf(ph);
#pragma unroll
    for (int cc = 0; cc < 4; ++cc) {
        const float yr = acr[cc] * c - aci[cc] * s;
        const float yi = acr[cc] * s + aci[cc] * c;
        const int coil = lane * 4 + cc;
        const size_t ob = ((size_t)(b * NCOILS + coil) * 2) * KLEN + m;
        out[ob]        = yr;
        out[ob + KLEN] = yi;
    }
}

// ---------------------------------------------------------------------------
// Fallback (tiny ws): one thread per point, original layout. General math.
// ---------------------------------------------------------------------------
__global__ __launch_bounds__(256) void interp_fallback(
    const float* __restrict__ om,
    const float* __restrict__ t0,
    const float* __restrict__ t1,
    const float* __restrict__ x,
    float*       __restrict__ out)
{
    const int p = blockIdx.x * blockDim.x + threadIdx.x;
    const int b = p >> 18;
    const int m = p & (KLEN - 1);

    const float om0 = om[(size_t)(b * 2 + 0) * KLEN + m];
    const float om1 = om[(size_t)(b * 2 + 1) * KLEN + m];
    const float TWO_PI = 6.2831853071795864769f;
    const float tm0 = (om0 * 512.0f) / TWO_PI;
    const float tm1 = (om1 * 512.0f) / TWO_PI;
    const float koff0 = 1.0f + floorf(tm0 - 3.0f);
    const float koff1 = 1.0f + floorf(tm1 - 3.0f);
    const int k0 = (int)koff0, k1 = (int)koff1;

    float c0r[6], c0i[6], c1r[6], c1i[6];
    int roff[6], coff[6];
#pragma unroll
    for (int j = 0; j < 6; ++j) {
        const float g0 = koff0 + (float)j;
        const int d0 = (int)rintf((tm0 - g0) * 1024.0f) + TBL_CTR;
        c0r[j] = t0[d0];
        c0i[j] = t0[TBL_LEN + d0];
        const float g1 = koff1 + (float)j;
        const int d1 = (int)rintf((tm1 - g1) * 1024.0f) + TBL_CTR;
        c1r[j] = t1[d1];
        c1i[j] = t1[TBL_LEN + d1];
        roff[j] = (k0 + j) & 511;
        coff[j] = (k1 + j) & 511;
    }

    float accr[NCOILS], acci[NCOILS];
#pragma unroll
    for (int c = 0; c < NCOILS; ++c) { accr[c] = 0.f; acci[c] = 0.f; }

    const float* xb = x + (size_t)b * NCOILS * 2 * PLANE;
#pragma unroll
    for (int j0 = 0; j0 < 6; ++j0) {
        const float ar = c0r[j0], ai = c0i[j0];
        const int rb = roff[j0] * GY;
#pragma unroll
        for (int j1 = 0; j1 < 6; ++j1) {
            const float br = c1r[j1], bi = c1i[j1];
            const float cr = ar * br - ai * bi;
            const float ci = ar * bi + ai * br;
            const int ai_idx = rb + coff[j1];
#pragma unroll
            for (int c = 0; c < NCOILS; ++c) {
                const float dr = xb[(size_t)c * (2 * PLANE) + ai_idx];
                const float di = xb[(size_t)c * (2 * PLANE) + PLANE + ai_idx];
                accr[c] += cr * dr - ci * di;
                acci[c] += cr * di + ci * dr;
            }
        }
    }

    const float ph = om0 * 128.0f + om1 * 128.0f;
    const float s = sinf(ph), c = cosf(ph);
#pragma unroll
    for (int cc = 0; cc < NCOILS; ++cc) {
        const float yr = accr[cc] * c - acci[cc] * s;
        const float yi = accr[cc] * s + acci[cc] * c;
        size_t ob = ((size_t)(b * NCOILS + cc) * 2) * KLEN + m;
        out[ob]        = yr;
        out[ob + KLEN] = yi;
    }
}

extern "C" void kernel_launch(void* const* d_in, const int* in_sizes, int n_in,
                              void* d_out, int out_size, void* d_ws, size_t ws_size,
                              hipStream_t stream)
{
    const float* x  = (const float*)d_in[0];
    const float* om = (const float*)d_in[1];
    const float* t0 = (const float*)d_in[2];
    const float* t1 = (const float*)d_in[3];
    float* out = (float*)d_out;

    char* ws = (char*)d_ws;
    const size_t xt_bytes = (size_t)NBATCH * PLANE * NCOILS * 2 * sizeof(__half);

    if (ws_size >= (size_t)WS_TOTAL) {
        float4*   xt     = (float4*)(ws + WS_XT);
        float4*   osort  = (float4*)(ws + WS_OSORT);
        unsigned* bhist  = (unsigned*)(ws + WS_BHIST);
        unsigned* btot   = (unsigned*)(ws + WS_BTOT);
        unsigned* bbase  = (unsigned*)(ws + WS_BBASE);
        unsigned* fwd    = (unsigned*)(ws + WS_FWD);

        transpose_hist<<<TBLKS + NBLK, 256, 0, stream>>>(x, xt, om, bhist);
        scan_bins<<<NBINS / 16, 1024, 0, stream>>>(bhist, btot);
        scatter2<<<NBLK, 1024, 0, stream>>>(om, bhist, btot, bbase, fwd);
        interp_bins<<<NBINS, 512, 0, stream>>>(om, t0, t1, xt, bbase, fwd, osort);
        unsort_kernel<<<NPTS / 1024, 1024, 0, stream>>>(osort, out);
    } else if (ws_size >= xt_bytes) {
        float4* xt = (float4*)ws;
        transpose_hist<<<TBLKS, 256, 0, stream>>>(x, xt, om, nullptr);
        interp_direct<<<NPTS * 4 / 256, 256, 0, stream>>>(om, t0, t1, xt, out);
    } else {
        interp_fallback<<<NPTS / 256, 256, 0, stream>>>(om, t0, t1, x, out);
    }
}

// Round 17
// 187.285 us; speedup vs baseline: 1.0288x; 1.0053x over previous
//
#include <hip/hip_runtime.h>
#include <hip/hip_fp16.h>

// KbInterpForw: table-based KB NUFFT interpolation, forward.
// x: (2,16,2,512,512) f32, om: (2,2,262144) f32, tables: (2,6145) f32 each.
// out: (2,16,2,262144) f32.
//
// R23 (on R22's 188.3 us):
//  - transpose_hist: histogram blocks moved to the FRONT of the grid
//    (blockIdx < NBLK). They were at the END -> ran as a ~1-block/CU
//    latency-bound TAIL after all 8192 transpose blocks drained (~8-12 us
//    nearly serial). First, they overlap the BW-bound transpose body and
//    finish inside its shadow. Same data, same determinism.
//  - om-gather lane-split idea rejected: both lanes of a pair load the SAME
//    address -> wave coalescer already broadcasts; no traffic to save.
//  - Everything else frozen: R22 fwd-only sort artifact (scatter writes
//    only fwd[pos]=id; interp writes osort[id]; streaming unsort), R21 XCD
//    bin swizzle, R19 block-major blockHist, TQ=5 tile, 2-lane real-weight
//    DPP interp.

#define KLEN      262144      // 2^18
#define GX        512
#define GY        512
#define NCOILS    16
#define NBATCH    2
#define TBL_LEN   6145        // 6*1024+1
#define TBL_CTR   3072
#define PLANE     (GX*GY)
#define NPTS      (NBATCH*KLEN)
#define NBINS     2048        // NBATCH * 32*32 tiles
#define NBLK      256         // sort blocks
#define PPB       2048        // points per sort block (NPTS/NBLK)
#define TBLKS     (NBATCH*PLANE/256)   // 8192 transpose blocks

#define TROWS     21          // 16 + 5 halo
#define TQ        5           // float4 slots per record in LDS (4 used + 1 pad)

typedef _Float16 half2_t __attribute__((ext_vector_type(2)));
struct alignas(16) H8 { half2_t h[4]; };   // 4 coils' (re,im) fp16 = 16 B

// ---------------------------------------------------------------------------
// ws layout (bytes). blockHist/btot alias the osort region (dead before
// interp writes osort). bbase and fwd live OUTSIDE osort: both are read by
// interp while osort is being written.
// ---------------------------------------------------------------------------
#define WS_XT       0                         // 33554432  fp16 grid records
#define WS_OSORT    33554432                  // 33554432  fp16 outputs (id-ordered)
#define WS_BHIST    33554432                  //  2097152  u32 [NBLK][NBINS] (alias osort)
#define WS_BTOT     (33554432+2097152)        //     8192  u32 [NBINS]      (alias osort)
#define WS_BBASE    67108864                  //     8192  u32 [NBINS]  NOT aliased
#define WS_FWD      (67108864+8192)           //  2097152  u32 id per sorted pos
#define WS_TOTAL    75497472

__device__ inline int point_bin(float om0, float om1)
{
    const float TWO_PI = 6.2831853071795864769f;
    const float tm0 = (om0 * 512.0f) / TWO_PI;
    const float tm1 = (om1 * 512.0f) / TWO_PI;
    const int cx = ((int)floorf(tm0)) & 511;
    const int cy = ((int)floorf(tm1)) & 511;
    return ((cx >> 4) << 5) | (cy >> 4);      // [0, 1024)
}

// quad-perm broadcast of a 32-bit value with explicit control byte. VALU op.
// Sources must be active lanes (we only reference the reader's own pair).
template<int CTRL>
__device__ inline int qbci(int i)
{
    return __builtin_amdgcn_mov_dpp(i, CTRL, 0xf, 0xf, true);
}
#define DPP_EVEN 0xA0   // [0,0,2,2]: read even lane of own pair
#define DPP_ODD  0xF5   // [1,1,3,3]: read odd lane of own pair

__device__ inline half2_t h2bits(int i)
{
    half2_t r;
    __builtin_memcpy(&r, &i, 4);
    return r;
}

// ---------------------------------------------------------------------------
// Fused hist+transpose. With blockHist != nullptr: blocks [0, NBLK) run the
// per-block LDS histogram (FIRST, so they overlap the transpose body instead
// of tailing it); blocks [NBLK, NBLK+TBLKS) transpose 256 consecutive cells
// via LDS. With blockHist == nullptr (grid=TBLKS): all blocks transpose.
// ---------------------------------------------------------------------------
__global__ __launch_bounds__(256) void transpose_hist(
    const float* __restrict__ x, float4* __restrict__ xt,
    const float* __restrict__ om, unsigned* __restrict__ blockHist)
{
    __shared__ float s[32][260];   // 33280 B; hist aliases first 8192 B
    const int t = threadIdx.x;

    if (blockHist != nullptr && blockIdx.x < NBLK) {
        // ---- histogram body (256 threads, 8 iters) ----------------------
        unsigned* h = (unsigned*)s;               // [NBINS]
        const int blk = blockIdx.x;
#pragma unroll
        for (int i = 0; i < NBINS / 256; ++i) h[t + i * 256] = 0u;
        __syncthreads();
#pragma unroll
        for (int i = 0; i < PPB / 256; ++i) {
            const int id = blk * PPB + i * 256 + t;
            const int b = id >> 18, m = id & (KLEN - 1);
            const float om0 = om[(size_t)(b * 2 + 0) * KLEN + m];
            const float om1 = om[(size_t)(b * 2 + 1) * KLEN + m];
            const int g = (b << 10) | point_bin(om0, om1);
            atomicAdd(&h[g], 1u);
        }
        __syncthreads();
#pragma unroll
        for (int i = 0; i < NBINS / 256; ++i) {
            const int bin = t + i * 256;
            blockHist[(size_t)blk * NBINS + bin] = h[bin];   // coalesced row
        }
        return;
    }

    // ---- transpose body -------------------------------------------------
    const int blk   = (blockHist != nullptr) ? (blockIdx.x - NBLK)
                                             : blockIdx.x;    // [0, TBLKS)
    const int base  = blk * 256;
    const int b     = base >> 18;
    const int cell0 = base & (PLANE - 1);

    const float* xb = x + (size_t)b * 32 * PLANE + cell0;
#pragma unroll
    for (int i = 0; i < 8; ++i) {
        const int fidx = i * 256 + t;        // [0, 2048)
        const int pl = fidx >> 6;            // wave-uniform plane
        const int j  = fidx & 63;
        const float4 v = *(const float4*)(xb + (size_t)pl * PLANE + j * 4);
        *(float4*)&s[pl][j * 4] = v;
    }
    __syncthreads();
#pragma unroll
    for (int i = 0; i < 4; ++i) {
        const int chunk = i * 256 + t;       // [0, 1024)
        const int cell = chunk >> 2, q = chunk & 3;
        H8 rec;
#pragma unroll
        for (int cc = 0; cc < 4; ++cc) {
            const int c = q * 4 + cc;
            rec.h[cc] = half2_t{(_Float16)s[2 * c][cell],
                                (_Float16)s[2 * c + 1][cell]};
        }
        xt[((size_t)b * PLANE + cell0 + cell) * 4 + q] = *(const float4*)&rec;
    }
}

// ---------------------------------------------------------------------------
// Sort pass 2: exclusive scan over blocks for each bin, block-major layout.
// Each block handles 16 consecutive bins: LDS-transpose a 256x16 panel
// (coalesced loads/stores), wave w scans bin column w via __shfl_up.
// Grid = NBINS/16 = 128 blocks x 1024 threads.
// ---------------------------------------------------------------------------
__global__ __launch_bounds__(1024) void scan_bins(
    unsigned* __restrict__ blockHist, unsigned* __restrict__ binTotal)
{
    __shared__ unsigned sh[256][17];          // [sortblk][bin-in-group]+pad
    const int t    = threadIdx.x;
    const int bin0 = blockIdx.x * 16;
    const int col  = t & 15, row0 = t >> 4;   // 64 rows per pass
#pragma unroll
    for (int p = 0; p < 4; ++p) {
        const int row = row0 + p * 64;
        sh[row][col] = blockHist[(size_t)row * NBINS + bin0 + col];
    }
    __syncthreads();

    const int lane = t & 63, wave = t >> 6;   // wave w owns bin0+w
    unsigned v[4];
#pragma unroll
    for (int k = 0; k < 4; ++k) v[k] = sh[lane * 4 + k][wave];
    const unsigned tot = v[0] + v[1] + v[2] + v[3];
    unsigned s = tot;
#pragma unroll
    for (int d = 1; d < 64; d <<= 1) {
        const unsigned x = __shfl_up(s, d);
        if (lane >= d) s += x;
    }
    unsigned excl = s - tot;                  // prefix for lane's 4 rows
#pragma unroll
    for (int k = 0; k < 4; ++k) { const unsigned nv = excl; excl += v[k]; v[k] = nv; }
    __syncthreads();                          // reuse sh for writeback
#pragma unroll
    for (int k = 0; k < 4; ++k) sh[lane * 4 + k][wave] = v[k];
    if (lane == 63) binTotal[bin0 + wave] = s;
    __syncthreads();
#pragma unroll
    for (int p = 0; p < 4; ++p) {
        const int row = row0 + p * 64;
        blockHist[(size_t)row * NBINS + bin0 + col] = sh[row][col];
    }
}

// ---------------------------------------------------------------------------
// Sort pass 3: final positions. Wave-based scan of btot gives bin bases;
// the block's own blockHist row (exclusive prefix over blocks) is folded
// into bbs at preamble time, so the per-point lookup is LDS-only.
// Writes ONLY fwd[pos]=id (scattered 4 B). Block 0 publishes pure bin
// bases to global bbase for interp. 1024 threads.
// ---------------------------------------------------------------------------
__global__ __launch_bounds__(1024) void scatter2(
    const float*    __restrict__ om,
    const unsigned* __restrict__ blockHist,
    const unsigned* __restrict__ btot,
    unsigned* __restrict__ bbase,
    unsigned* __restrict__ fwd)
{
    __shared__ unsigned h[NBINS];
    __shared__ unsigned bbs[NBINS];
    __shared__ unsigned wsum[16];
    const int t = threadIdx.x, blk = blockIdx.x;
    const int lane = t & 63, wave = t >> 6;

    // exclusive scan of btot -> bin bases: wave scan + 1-barrier fixup
    const unsigned v0 = btot[t * 2], v1 = btot[t * 2 + 1];
    const unsigned tot = v0 + v1;
    unsigned s = tot;
#pragma unroll
    for (int d = 1; d < 64; d <<= 1) {
        const unsigned x = __shfl_up(s, d);
        if (lane >= d) s += x;
    }
    if (lane == 63) wsum[wave] = s;
    // own row of scanned blockHist (coalesced 8 KB)
    const unsigned bh0 = blockHist[(size_t)blk * NBINS + t * 2];
    const unsigned bh1 = blockHist[(size_t)blk * NBINS + t * 2 + 1];
#pragma unroll
    for (int i = 0; i < NBINS / 1024; ++i) h[t + i * 1024] = 0u;
    __syncthreads();
    unsigned wp = 0;
#pragma unroll
    for (int i = 0; i < 16; ++i) wp += (i < wave) ? wsum[i] : 0u;
    const unsigned excl = wp + s - tot;
    bbs[t * 2]     = excl + bh0;              // binbase + row prefix folded
    bbs[t * 2 + 1] = excl + v0 + bh1;
    if (blk == 0) {                           // publish pure bases for interp
        bbase[t * 2]     = excl;
        bbase[t * 2 + 1] = excl + v0;
    }
    __syncthreads();

#pragma unroll
    for (int i = 0; i < PPB / 1024; ++i) {
        const int id = blk * PPB + i * 1024 + t;
        const int b = id >> 18, m = id & (KLEN - 1);
        const float om0 = om[(size_t)(b * 2 + 0) * KLEN + m];
        const float om1 = om[(size_t)(b * 2 + 1) * KLEN + m];
        const int g = (b << 10) | point_bin(om0, om1);
        const unsigned r = atomicAdd(&h[g], 1u);
        const unsigned pos = bbs[g] + r;       // LDS-only lookup
        fwd[pos] = (unsigned)id;               // scattered 4 B (only artifact)
    }
}

// ---------------------------------------------------------------------------
// Main interp: ONE BLOCK PER BIN, 512 threads, XCD-aware bin swizzle. Reads
// fwd[pos] coalesced, recovers m (b known from bin), gathers om0/om1 from
// the L2-hot om planes (pair lanes share the address -> wave broadcast).
// Stage the bin's 21x21 halo tile into LDS (proven TQ=5 record-pad layout).
// 2 LANES PER POINT, 8 coils each; REAL-TABLE weights, DPP pair-share.
// Output record written to osort[id] (id-ordered, scattered full-line 64 B
// stores) so unsort is pure streaming.
// ---------------------------------------------------------------------------
__global__ __launch_bounds__(512) void interp_bins(
    const float*    __restrict__ om,
    const float*    __restrict__ t0,
    const float*    __restrict__ t1,
    const float4*   __restrict__ xt,
    const unsigned* __restrict__ bbase,
    const unsigned* __restrict__ fwd,
    float4*         __restrict__ osort)
{
    __shared__ float4 tile[TROWS * TROWS * TQ];   // 2205 f4 = 35280 B
    // XCD swizzle: round-robin dispatch puts (blockIdx & 7) on one XCD;
    // give each XCD a contiguous 256-bin range (8 tile rows).
    const int bin = ((blockIdx.x & 7) << 8) | (blockIdx.x >> 3);
    const int t   = threadIdx.x;
    const int b   = bin >> 10;
    const int cx0 = ((bin >> 5) & 31) << 4;
    const int cy0 = (bin & 31) << 4;

    const unsigned p0  = bbase[bin];
    const unsigned p1e = (bin == NBINS - 1) ? (unsigned)NPTS : bbase[bin + 1];
    const int cnt = (int)(p1e - p0);

    // ---- stage halo tile: 441 records x 4 chunks, coalesced rows --------
    const float4* rec = xt + ((size_t)b << 20);   // b * PLANE * 4 chunks
    for (int f = t; f < TROWS * TROWS * 4; f += 512) {
        const int r = f >> 2, q = f & 3;
        const int row = r / TROWS;                // const-div -> magic mul
        const int col = r - row * TROWS;
        const int gr = (cx0 - 2 + row) & 511;
        const int gc = (cy0 - 2 + col) & 511;
        tile[r * TQ + q] = rec[(((size_t)((gr << 9) | gc)) << 2) + q];
    }
    __syncthreads();

    const float* omb0 = om + (size_t)(b * 2 + 0) * KLEN;
    const float* omb1 = om + (size_t)(b * 2 + 1) * KLEN;

    const int lane = t & 1;                    // pair lane
    for (int base = 0; base < cnt; base += 256) {
        const int idx = base + (t >> 1);
        if (idx >= cnt) continue;              // lane-pairs skip together
        const int pos = (int)p0 + idx;

        const unsigned oid = fwd[pos];         // coalesced
        const int m = (int)(oid & (KLEN - 1));
        const float om0 = omb0[m];             // L2-hot gather (pair-broadcast)
        const float om1 = omb1[m];

        const float TWO_PI = 6.2831853071795864769f;
        const float tm0 = (om0 * 512.0f) / TWO_PI;
        const float tm1 = (om1 * 512.0f) / TWO_PI;

        const float koff0 = 1.0f + floorf(tm0 - 3.0f);
        const float koff1 = 1.0f + floorf(tm1 - 3.0f);
        const int   k0    = (int)koff0;
        const int   k1    = (int)koff1;

        // c0: all 6 row weights, every lane. c1: this lane's 3 j1 weights.
        float c0r[6];
        int   loff[6];
#pragma unroll
        for (int j = 0; j < 6; ++j) {
            const float g0 = koff0 + (float)j;
            const int   d0 = (int)rintf((tm0 - g0) * 1024.0f) + TBL_CTR;
            c0r[j] = t0[d0];
            loff[j] = ((k1 + j - cy0 + 2) & 511) * TQ;   // in [0, 20]*TQ
        }
        const int j1o = 3 * lane;              // own j1 base: 0 or 3
        float c1r_[3];
#pragma unroll
        for (int k = 0; k < 3; ++k) {
            const int d1 = (int)rintf((tm1 - (koff1 + (float)(j1o + k))) * 1024.0f)
                           + TBL_CTR;
            c1r_[k] = t1[d1];
        }

        // acr[0..3]: slot (lane)   -> coils 4*lane   .. 4*lane+3
        // acr[4..7]: slot (lane+2) -> coils 4*lane+8 .. 4*lane+11
        float acr[8], aci[8];
#pragma unroll
        for (int c = 0; c < 8; ++c) { acr[c] = 0.f; aci[c] = 0.f; }

#define KB_DO_J1(JJ, P1, P2)                                                  \
        do {                                                                  \
            const half2_t p1 = (P1);                                          \
            const half2_t p2 = (P2);                                          \
            const float4 raw0 = rowp[loff[JJ]];                               \
            const float4 raw1 = rowp[loff[JJ] + 2];                           \
            const H8 v0 = *(const H8*)&raw0;                                  \
            const H8 v1 = *(const H8*)&raw1;                                  \
            _Pragma("unroll")                                                 \
            for (int cc = 0; cc < 4; ++cc) {                                  \
                acr[cc]   = __builtin_amdgcn_fdot2(v0.h[cc], p1, acr[cc],   false);\
                aci[cc]   = __builtin_amdgcn_fdot2(v0.h[cc], p2, aci[cc],   false);\
                acr[4+cc] = __builtin_amdgcn_fdot2(v1.h[cc], p1, acr[4+cc], false);\
                aci[4+cc] = __builtin_amdgcn_fdot2(v1.h[cc], p2, aci[4+cc], false);\
            }                                                                 \
        } while (0)

#pragma unroll
        for (int j0 = 0; j0 < 6; ++j0) {
            const int rIdx = (k0 + j0 - cx0 + 2) & 511;  // in [0, 20]
            const float4* rowp = &tile[rIdx * (TROWS * TQ) + lane];
            const float ar = c0r[j0];
            // this lane's 3 real weights, packed fp16x2 (RNE casts)
            const float wA = ar * c1r_[0];
            const float wB = ar * c1r_[1];
            const float wC = ar * c1r_[2];
            const half2_t pk01 = {(_Float16)wA, (_Float16)wB};
            const half2_t pk2  = {(_Float16)wC, (_Float16)0.0f};
            int i01, i2;
            __builtin_memcpy(&i01, &pk01, 4);
            __builtin_memcpy(&i2,  &pk2, 4);
            // pair-share: 4 DPP broadcasts cover all 6 j1 weights
            const int e01 = qbci<DPP_EVEN>(i01);
            const int e2  = qbci<DPP_EVEN>(i2);
            const int o01 = qbci<DPP_ODD >(i01);
            const int o2  = qbci<DPP_ODD >(i2);

            // j1 slot weights: (w,0) for re-acc, (0,w) for im-acc
            KB_DO_J1(0, h2bits(e01 & 0xffff),       h2bits(e01 << 16));
            KB_DO_J1(1, h2bits((int)((unsigned)e01 >> 16)), h2bits(e01 & (int)0xffff0000u));
            KB_DO_J1(2, h2bits(e2 & 0xffff),        h2bits(e2 << 16));
            KB_DO_J1(3, h2bits(o01 & 0xffff),       h2bits(o01 << 16));
            KB_DO_J1(4, h2bits((int)((unsigned)o01 >> 16)), h2bits(o01 & (int)0xffff0000u));
            KB_DO_J1(5, h2bits(o2 & 0xffff),        h2bits(o2 << 16));
        }
#undef KB_DO_J1

        // phase twist: exp(i * (om0+om1)*128); |ph| <= 128 rev -> native ok
        const float ph = om0 * 128.0f + om1 * 128.0f;
        const float s = __sinf(ph), c = __cosf(ph);

        // id-ordered output: the lane pair covers one full 64 B line
        float4* op = osort + (size_t)oid * 4 + lane;
#pragma unroll
        for (int q = 0; q < 2; ++q) {
            H8 outrec;
#pragma unroll
            for (int cc = 0; cc < 4; ++cc) {
                const int a = q * 4 + cc;
                const float yr = acr[a] * c - aci[a] * s;
                const float yi = acr[a] * s + aci[a] * c;
                outrec.h[cc] = half2_t{(_Float16)yr, (_Float16)yi};
            }
            op[q * 2] = *(const float4*)&outrec;
        }
    }
}

// ---------------------------------------------------------------------------
// Unsort: PURE STREAMING. osort is id-ordered: thread id reads its 64 B
// record coalesced and stores coalesced into the final (b,c,ri,m) layout.
// ---------------------------------------------------------------------------
__global__ __launch_bounds__(1024) void unsort_kernel(
    const float4*   __restrict__ osort,
    float*          __restrict__ out)
{
    const int id = blockIdx.x * blockDim.x + threadIdx.x;   // [0, NPTS)
    const int b = id >> 18, m = id & (KLEN - 1);
    const float4* rp = osort + (size_t)id * 4;

    float4 raw[4];
#pragma unroll
    for (int q = 0; q < 4; ++q) raw[q] = rp[q];

    float* ob = out + (size_t)b * NCOILS * 2 * KLEN + m;
#pragma unroll
    for (int q = 0; q < 4; ++q) {
        const H8 v = *(const H8*)&raw[q];
#pragma unroll
        for (int cc = 0; cc < 4; ++cc) {
            const int coil = q * 4 + cc;
            ob[(size_t)(2 * coil)     * KLEN] = (float)v.h[cc].x;
            ob[(size_t)(2 * coil + 1) * KLEN] = (float)v.h[cc].y;
        }
    }
}

// ---------------------------------------------------------------------------
// Middle path (ws >= xt only): direct-order interp (4 lanes/point).
// Keeps the general complex-table math (not perf-critical).
// ---------------------------------------------------------------------------
__global__ __launch_bounds__(256) void interp_direct(
    const float*  __restrict__ om,
    const float*  __restrict__ t0,
    const float*  __restrict__ t1,
    const float4* __restrict__ xt,
    float*        __restrict__ out)
{
    const int tid  = blockIdx.x * blockDim.x + threadIdx.x;
    const int lane = tid & 3;
    const int p    = tid >> 2;
    const int b    = p >> 18;
    const int m    = p & (KLEN - 1);

    const float om0 = om[(size_t)(b * 2 + 0) * KLEN + m];
    const float om1 = om[(size_t)(b * 2 + 1) * KLEN + m];

    const float TWO_PI = 6.2831853071795864769f;
    const float tm0 = (om0 * 512.0f) / TWO_PI;
    const float tm1 = (om1 * 512.0f) / TWO_PI;
    const float koff0 = 1.0f + floorf(tm0 - 3.0f);
    const float koff1 = 1.0f + floorf(tm1 - 3.0f);
    const int k0 = (int)koff0, k1 = (int)koff1;

    float c0r[6], c0i[6], c1r[6], c1i[6];
    int coff[6];
#pragma unroll
    for (int j = 0; j < 6; ++j) {
        const float g0 = koff0 + (float)j;
        const int d0 = (int)rintf((tm0 - g0) * 1024.0f) + TBL_CTR;
        c0r[j] = t0[d0];
        c0i[j] = t0[TBL_LEN + d0];
        const float g1 = koff1 + (float)j;
        const int d1 = (int)rintf((tm1 - g1) * 1024.0f) + TBL_CTR;
        c1r[j] = t1[d1];
        c1i[j] = t1[TBL_LEN + d1];
        coff[j] = ((k1 + j) & 511) << 2;
    }

    const float4* rec = xt + ((size_t)b << 20);
    float acr[4] = {0.f, 0.f, 0.f, 0.f};
    float aci[4] = {0.f, 0.f, 0.f, 0.f};
#pragma unroll
    for (int j0 = 0; j0 < 6; ++j0) {
        const int roff = (k0 + j0) & 511;
        const float4* rowp = rec + ((size_t)roff << 11) + lane;
        const float ar = c0r[j0], ai = c0i[j0];
#pragma unroll
        for (int j1 = 0; j1 < 6; ++j1) {
            const float br = c1r[j1], bi = c1i[j1];
            const float cr = ar * br - ai * bi;
            const float ci = ar * bi + ai * br;
            const half2_t p1 = {(_Float16)cr, (_Float16)(-ci)};
            const half2_t p2 = {(_Float16)ci, (_Float16)cr};
            const float4 raw = rowp[coff[j1]];
            const H8 v = *(const H8*)&raw;
#pragma unroll
            for (int cc = 0; cc < 4; ++cc) {
                acr[cc] = __builtin_amdgcn_fdot2(v.h[cc], p1, acr[cc], false);
                aci[cc] = __builtin_amdgcn_fdot2(v.h[cc], p2, aci[cc], false);
            }
        }
    }

    const float ph = om0 * 128.0f + om1 * 128.0f;
    const float s = sinf(ph), c = cosf(ph);
#pragma unroll
    for (int cc = 0; cc < 4; ++cc) {
        const float yr = acr[cc] * c - aci[cc] * s;
        const float yi = acr[cc] * s + aci[cc] * c;
        const int coil = lane * 4 + cc;
        const size_t ob = ((size_t)(b * NCOILS + coil) * 2) * KLEN + m;
        out[ob]        = yr;
        out[ob + KLEN] = yi;
    }
}

// ---------------------------------------------------------------------------
// Fallback (tiny ws): one thread per point, original layout. General math.
// ---------------------------------------------------------------------------
__global__ __launch_bounds__(256) void interp_fallback(
    const float* __restrict__ om,
    const float* __restrict__ t0,
    const float* __restrict__ t1,
    const float* __restrict__ x,
    float*       __restrict__ out)
{
    const int p = blockIdx.x * blockDim.x + threadIdx.x;
    const int b = p >> 18;
    const int m = p & (KLEN - 1);

    const float om0 = om[(size_t)(b * 2 + 0) * KLEN + m];
    const float om1 = om[(size_t)(b * 2 + 1) * KLEN + m];
    const float TWO_PI = 6.2831853071795864769f;
    const float tm0 = (om0 * 512.0f) / TWO_PI;
    const float tm1 = (om1 * 512.0f) / TWO_PI;
    const float koff0 = 1.0f + floorf(tm0 - 3.0f);
    const float koff1 = 1.0f + floorf(tm1 - 3.0f);
    const int k0 = (int)koff0, k1 = (int)koff1;

    float c0r[6], c0i[6], c1r[6], c1i[6];
    int roff[6], coff[6];
#pragma unroll
    for (int j = 0; j < 6; ++j) {
        const float g0 = koff0 + (float)j;
        const int d0 = (int)rintf((tm0 - g0) * 1024.0f) + TBL_CTR;
        c0r[j] = t0[d0];
        c0i[j] = t0[TBL_LEN + d0];
        const float g1 = koff1 + (float)j;
        const int d1 = (int)rintf((tm1 - g1) * 1024.0f) + TBL_CTR;
        c1r[j] = t1[d1];
        c1i[j] = t1[TBL_LEN + d1];
        roff[j] = (k0 + j) & 511;
        coff[j] = (k1 + j) & 511;
    }

    float accr[NCOILS], acci[NCOILS];
#pragma unroll
    for (int c = 0; c < NCOILS; ++c) { accr[c] = 0.f; acci[c] = 0.f; }

    const float* xb = x + (size_t)b * NCOILS * 2 * PLANE;
#pragma unroll
    for (int j0 = 0; j0 < 6; ++j0) {
        const float ar = c0r[j0], ai = c0i[j0];
        const int rb = roff[j0] * GY;
#pragma unroll
        for (int j1 = 0; j1 < 6; ++j1) {
            const float br = c1r[j1], bi = c1i[j1];
            const float cr = ar * br - ai * bi;
            const float ci = ar * bi + ai * br;
            const int ai_idx = rb + coff[j1];
#pragma unroll
            for (int c = 0; c < NCOILS; ++c) {
                const float dr = xb[(size_t)c * (2 * PLANE) + ai_idx];
                const float di = xb[(size_t)c * (2 * PLANE) + PLANE + ai_idx];
                accr[c] += cr * dr - ci * di;
                acci[c] += cr * di + ci * dr;
            }
        }
    }

    const float ph = om0 * 128.0f + om1 * 128.0f;
    const float s = sinf(ph), c = cosf(ph);
#pragma unroll
    for (int cc = 0; cc < NCOILS; ++cc) {
        const float yr = accr[cc] * c - acci[cc] * s;
        const float yi = accr[cc] * s + acci[cc] * c;
        size_t ob = ((size_t)(b * NCOILS + cc) * 2) * KLEN + m;
        out[ob]        = yr;
        out[ob + KLEN] = yi;
    }
}

extern "C" void kernel_launch(void* const* d_in, const int* in_sizes, int n_in,
                              void* d_out, int out_size, void* d_ws, size_t ws_size,
                              hipStream_t stream)
{
    const float* x  = (const float*)d_in[0];
    const float* om = (const float*)d_in[1];
    const float* t0 = (const float*)d_in[2];
    const float* t1 = (const float*)d_in[3];
    float* out = (float*)d_out;

    char* ws = (char*)d_ws;
    const size_t xt_bytes = (size_t)NBATCH * PLANE * NCOILS * 2 * sizeof(__half);

    if (ws_size >= (size_t)WS_TOTAL) {
        float4*   xt     = (float4*)(ws + WS_XT);
        float4*   osort  = (float4*)(ws + WS_OSORT);
        unsigned* bhist  = (unsigned*)(ws + WS_BHIST);
        unsigned* btot   = (unsigned*)(ws + WS_BTOT);
        unsigned* bbase  = (unsigned*)(ws + WS_BBASE);
        unsigned* fwd    = (unsigned*)(ws + WS_FWD);

        transpose_hist<<<TBLKS + NBLK, 256, 0, stream>>>(x, xt, om, bhist);
        scan_bins<<<NBINS / 16, 1024, 0, stream>>>(bhist, btot);
        scatter2<<<NBLK, 1024, 0, stream>>>(om, bhist, btot, bbase, fwd);
        interp_bins<<<NBINS, 512, 0, stream>>>(om, t0, t1, xt, bbase, fwd, osort);
        unsort_kernel<<<NPTS / 1024, 1024, 0, stream>>>(osort, out);
    } else if (ws_size >= xt_bytes) {
        float4* xt = (float4*)ws;
        transpose_hist<<<TBLKS, 256, 0, stream>>>(x, xt, om, nullptr);
        interp_direct<<<NPTS * 4 / 256, 256, 0, stream>>>(om, t0, t1, xt, out);
    } else {
        interp_fallback<<<NPTS / 256, 256, 0, stream>>>(om, t0, t1, x, out);
    }
}